// Round 3
// baseline (418.079 us; speedup 1.0000x reference)
//
#include <hip/hip_runtime.h>

#define NN 50000
#define ND (NN * 128)
#define SCAN_B 49   // ceil(NN / 1024)
#define LOG2E 1.4426950408889634f

typedef float f32x2 __attribute__((ext_vector_type(2)));

#if defined(__has_builtin)
#  if __has_builtin(__builtin_amdgcn_exp2f)
#    define EXP2F(x) __builtin_amdgcn_exp2f(x)
#  else
#    define EXP2F(x) exp2f(x)
#  endif
#else
#  define EXP2F(x) exp2f(x)
#endif

__device__ __forceinline__ float b2f(unsigned short u) {
    union { unsigned int i; float f; } v; v.i = ((unsigned int)u) << 16; return v.f;
}
__device__ __forceinline__ unsigned short f2b(float f) {      // RNE bf16 pack
    union { float f; unsigned int i; } v; v.f = f;
    return (unsigned short)((v.i + 0x7fffu + ((v.i >> 16) & 1u)) >> 16);
}
__device__ __forceinline__ unsigned int pack2(float lo, float hi) {
    return (unsigned int)f2b(lo) | ((unsigned int)f2b(hi) << 16);
}
__device__ __forceinline__ float unlo(unsigned int u) { return __uint_as_float(u << 16); }
__device__ __forceinline__ float unhi(unsigned int u) { return __uint_as_float(u & 0xFFFF0000u); }
__device__ __forceinline__ int clampi(int i, int lo, int hi) { return max(lo, min(i, hi)); }

// DPP lane ops (VALU pipe, no LDS traffic)
template<int CTRL>
__device__ __forceinline__ float dmov(float v) {
    return __int_as_float(__builtin_amdgcn_update_dpp(0, __float_as_int(v), CTRL, 0xF, 0xF, true));
}
template<int CTRL> __device__ __forceinline__ float dadd(float v) { return v + dmov<CTRL>(v); }
__device__ __forceinline__ float qsum(float v) { v = dadd<0xB1>(v); v = dadd<0x4E>(v); return v; }
__device__ __forceinline__ float rsum4(float v) { v = dadd<0x124>(v); v = dadd<0x128>(v); return v; }

// ---- dtype detection: flags[0]=1 if floats fp32; flags[1]=1 if edges int32 ----
__global__ __launch_bounds__(256) void detect(
    const unsigned short* __restrict__ feat_u, const unsigned int* __restrict__ ei_u,
    int* __restrict__ flags)
{
    int tid = threadIdx.x;
    int f32hit = 0;
    for (int i = tid; i < 8192; i += 256) {
        unsigned e = (feat_u[i] >> 7) & 0xFFu;
        if (e >= 0xC0u) f32hit = 1;
    }
    int i32hit = 0;
    for (int i = tid; i < 4096; i += 256)
        if (ei_u[2 * i + 1] != 0u) i32hit = 1;
    if (f32hit) atomicOr(&flags[0], 1);
    if (i32hit) atomicOr(&flags[1], 1);
}

// ---- one-time W/bias -> fp32 workspace (removes per-block convert in GEMMs) ----
__global__ __launch_bounds__(256) void prep_w(
    const void* __restrict__ W1, const void* __restrict__ B1,
    const void* __restrict__ W2, const void* __restrict__ B2,
    float* __restrict__ w1o, float* __restrict__ b1o,
    float* __restrict__ w2o, float* __restrict__ b2o,
    const int* __restrict__ flags)
{
    bool isF32 = flags[0] != 0;
    int idx = blockIdx.x * 256 + threadIdx.x;
    if (idx < 16384) {
        if (isF32) { w1o[idx] = ((const float*)W1)[idx]; w2o[idx] = ((const float*)W2)[idx]; }
        else {
            w1o[idx] = b2f(((const unsigned short*)W1)[idx]);
            w2o[idx] = b2f(((const unsigned short*)W2)[idx]);
        }
    }
    if (idx < 128) {
        if (isF32) { b1o[idx] = ((const float*)B1)[idx]; b2o[idx] = ((const float*)B2)[idx]; }
        else {
            b1o[idx] = b2f(((const unsigned short*)B1)[idx]);
            b2o[idx] = b2f(((const unsigned short*)B2)[idx]);
        }
    }
}

// ---- extract int32 src/trg + degree histogram ----
__global__ __launch_bounds__(256) void conv_hist(
    const void* __restrict__ eiRaw, int* __restrict__ srcA, int* __restrict__ trgA,
    int* __restrict__ deg, int m, const int* __restrict__ flags)
{
    int e = blockIdx.x * 256 + threadIdx.x;
    if (e >= m) return;
    int src, trg;
    if (flags[1]) { const int* p = (const int*)eiRaw; src = p[e]; trg = p[m + e]; }
    else { const long long* p = (const long long*)eiRaw; src = (int)p[e]; trg = (int)p[m + e]; }
    src = clampi(src, 0, NN - 1);
    trg = clampi(trg, 0, NN - 1);
    srcA[e] = src; trgA[e] = trg;
    atomicAdd(&deg[trg], 1);
}

// ---- exclusive scan of deg[NN] -> rowStart[NN+1] ----
__global__ __launch_bounds__(256) void scan1(
    const int* __restrict__ deg, int* __restrict__ rowStart, int* __restrict__ blkSum)
{
    __shared__ int lds[256];
    int blk = blockIdx.x, tid = threadIdx.x;
    int base = blk * 1024 + tid * 4;
    int v[4]; int s = 0;
    #pragma unroll
    for (int j = 0; j < 4; ++j) { int idx = base + j; v[j] = (idx < NN) ? deg[idx] : 0; s += v[j]; }
    lds[tid] = s; __syncthreads();
    for (int off = 1; off < 256; off <<= 1) {
        int x = (tid >= off) ? lds[tid - off] : 0;
        __syncthreads();
        lds[tid] += x;
        __syncthreads();
    }
    int excl = lds[tid] - s;
    if (tid == 255) blkSum[blk] = lds[tid];
    int run = excl;
    #pragma unroll
    for (int j = 0; j < 4; ++j) { int idx = base + j; if (idx < NN) rowStart[idx] = run; run += v[j]; }
}
__global__ __launch_bounds__(64) void scan2(
    int* __restrict__ blkSum, int* __restrict__ blkOff, int* __restrict__ rowStart, int m)
{
    int lane = threadIdx.x;
    int orig = (lane < SCAN_B) ? blkSum[lane] : 0;
    int v = orig;
    for (int off = 1; off < 64; off <<= 1) {
        int x = __shfl_up(v, off);
        if (lane >= off) v += x;
    }
    if (lane < SCAN_B) blkOff[lane] = v - orig;
    if (lane == 0) rowStart[NN] = m;
}
// scan3 also seeds cursor (replaces the D2D memcpy dispatch)
__global__ __launch_bounds__(256) void scan3(
    int* __restrict__ rowStart, const int* __restrict__ blkOff, int* __restrict__ cursor)
{
    int base = blockIdx.x * 1024 + threadIdx.x * 4;
    int off = blkOff[blockIdx.x];
    #pragma unroll
    for (int j = 0; j < 4; ++j) {
        int idx = base + j;
        if (idx < NN) { int v = rowStart[idx] + off; rowStart[idx] = v; cursor[idx] = v; }
    }
}

// ---- scatter edges into CSR bins ----
__global__ __launch_bounds__(256) void scatter_csr(
    const int* __restrict__ srcA, const int* __restrict__ trgA,
    int* __restrict__ cursor, int* __restrict__ eSrc, int m)
{
    int e = blockIdx.x * 256 + threadIdx.x;
    if (e >= m) return;
    int pos = atomicAdd(&cursor[trgA[e]], 1);
    eSrc[pos] = srcA[e];
}

// ---- GEMM1: XNh(bf16) = channel_normalize(feat @ W + b). W/bias fp32 (prepped).
// W streamed from global (L1/L2-cached, coalesced 512B panels). LDS = As only (16KB).
__global__ __launch_bounds__(256) void gemm_norm(
    const void* __restrict__ A, const float* __restrict__ W, const float* __restrict__ bias,
    unsigned short* __restrict__ XNh, const int* __restrict__ flags)
{
    __shared__ float As[32 * 128];
    int tid = threadIdx.x;
    int cg = tid & 31;                // cols 4cg..4cg+3
    int rg = tid >> 5;                // rows rg*4..rg*4+3 (of 32)
    int rowBase = blockIdx.x * 32;
    bool isF32 = flags[0] != 0;

    #pragma unroll
    for (int r = 0; r < 4; ++r) {
        int lrow = r * 8 + rg;
        int row = rowBase + lrow;
        float4 v = make_float4(0.f, 0.f, 0.f, 0.f);
        if (row < NN) {
            if (isF32) v = *(const float4*)&((const float*)A)[(long)row * 128 + cg * 4];
            else {
                ushort4 u = *(const ushort4*)&((const unsigned short*)A)[(long)row * 128 + cg * 4];
                v = make_float4(b2f(u.x), b2f(u.y), b2f(u.z), b2f(u.w));
            }
        }
        *(float4*)&As[lrow * 128 + cg * 4] = v;
    }
    float4 bb = *(const float4*)&bias[cg * 4];
    __syncthreads();

    float acc[4][4];
    #pragma unroll
    for (int i = 0; i < 4; ++i) { acc[i][0]=bb.x; acc[i][1]=bb.y; acc[i][2]=bb.z; acc[i][3]=bb.w; }

    #pragma unroll 2
    for (int k4 = 0; k4 < 32; ++k4) {
        float4 w[4], av[4];
        #pragma unroll
        for (int j = 0; j < 4; ++j)
            w[j] = *(const float4*)&W[(k4 * 4 + j) * 128 + cg * 4];
        #pragma unroll
        for (int i = 0; i < 4; ++i)
            av[i] = *(const float4*)&As[(rg * 4 + i) * 128 + k4 * 4];
        #pragma unroll
        for (int i = 0; i < 4; ++i) {
            const float a0 = av[i].x, a1 = av[i].y, a2 = av[i].z, a3 = av[i].w;
            acc[i][0] = fmaf(a0, w[0].x, fmaf(a1, w[1].x, fmaf(a2, w[2].x, fmaf(a3, w[3].x, acc[i][0]))));
            acc[i][1] = fmaf(a0, w[0].y, fmaf(a1, w[1].y, fmaf(a2, w[2].y, fmaf(a3, w[3].y, acc[i][1]))));
            acc[i][2] = fmaf(a0, w[0].z, fmaf(a1, w[1].z, fmaf(a2, w[2].z, fmaf(a3, w[3].z, acc[i][2]))));
            acc[i][3] = fmaf(a0, w[0].w, fmaf(a1, w[1].w, fmaf(a2, w[2].w, fmaf(a3, w[3].w, acc[i][3]))));
        }
    }
    #pragma unroll
    for (int i = 0; i < 4; ++i) {
        int row = rowBase + rg * 4 + i;
        float lss = acc[i][0]*acc[i][0] + acc[i][1]*acc[i][1] + acc[i][2]*acc[i][2] + acc[i][3]*acc[i][3];
        lss += __shfl_xor(lss, 1);
        lss += __shfl_xor(lss, 2);
        lss += __shfl_xor(lss, 4);
        float scale = 1.0f / fmaxf(sqrtf(lss), 1e-12f);
        if (row < NN) {
            float4 o; o.x = acc[i][0]*scale; o.y = acc[i][1]*scale; o.z = acc[i][2]*scale; o.w = acc[i][3]*scale;
            uint2 pk; pk.x = pack2(o.x, o.y); pk.y = pack2(o.z, o.w);
            *(uint2*)((char*)XNh + (long)row * 256 + cg * 8) = pk;
        }
    }
}

// ---- GEMM2: Out = A @ W + b (A fp32, W/bias fp32 prepped) ----
__global__ __launch_bounds__(256) void gemm_plain(
    const float* __restrict__ A, const float* __restrict__ W, const float* __restrict__ bias,
    float* __restrict__ Out)
{
    __shared__ float As[32 * 128];
    int tid = threadIdx.x;
    int cg = tid & 31;
    int rg = tid >> 5;
    int rowBase = blockIdx.x * 32;

    #pragma unroll
    for (int r = 0; r < 4; ++r) {
        int lrow = r * 8 + rg;
        int row = rowBase + lrow;
        float4 v = make_float4(0.f, 0.f, 0.f, 0.f);
        if (row < NN) v = *(const float4*)&A[(long)row * 128 + cg * 4];
        *(float4*)&As[lrow * 128 + cg * 4] = v;
    }
    float4 bb = *(const float4*)&bias[cg * 4];
    __syncthreads();

    float acc[4][4];
    #pragma unroll
    for (int i = 0; i < 4; ++i) { acc[i][0]=bb.x; acc[i][1]=bb.y; acc[i][2]=bb.z; acc[i][3]=bb.w; }

    #pragma unroll 2
    for (int k4 = 0; k4 < 32; ++k4) {
        float4 w[4], av[4];
        #pragma unroll
        for (int j = 0; j < 4; ++j)
            w[j] = *(const float4*)&W[(k4 * 4 + j) * 128 + cg * 4];
        #pragma unroll
        for (int i = 0; i < 4; ++i)
            av[i] = *(const float4*)&As[(rg * 4 + i) * 128 + k4 * 4];
        #pragma unroll
        for (int i = 0; i < 4; ++i) {
            const float a0 = av[i].x, a1 = av[i].y, a2 = av[i].z, a3 = av[i].w;
            acc[i][0] = fmaf(a0, w[0].x, fmaf(a1, w[1].x, fmaf(a2, w[2].x, fmaf(a3, w[3].x, acc[i][0]))));
            acc[i][1] = fmaf(a0, w[0].y, fmaf(a1, w[1].y, fmaf(a2, w[2].y, fmaf(a3, w[3].y, acc[i][1]))));
            acc[i][2] = fmaf(a0, w[0].z, fmaf(a1, w[1].z, fmaf(a2, w[2].z, fmaf(a3, w[3].z, acc[i][2]))));
            acc[i][3] = fmaf(a0, w[0].w, fmaf(a1, w[1].w, fmaf(a2, w[2].w, fmaf(a3, w[3].w, acc[i][3]))));
        }
    }
    #pragma unroll
    for (int i = 0; i < 4; ++i) {
        int row = rowBase + rg * 4 + i;
        if (row < NN) {
            float4 o; o.x = acc[i][0]; o.y = acc[i][1]; o.z = acc[i][2]; o.w = acc[i][3];
            *(float4*)&Out[(long)row * 128 + cg * 4] = o;
        }
    }
}

// ---- fused per-layer routing: 1 wave/node, all 3 iterations ----
// v4: first 16 edges (4/slot) unpacked ONCE into registers (f32x2 rz[4][4], static
// indices via full unroll); edges >=16 gathered from global each pass (L2-resident).
// No LDS at all. Guard conditions are slot-uniform -> DPP reductions stay exec-safe.
// Accumulation order per slot unchanged -> bit-identical to v3.
#define PROC_R(za0, za1, za2, za3) { \
    f32x2 dd_ = za0 * s0; \
    dd_ = __builtin_elementwise_fma(za1, s1, dd_); \
    dd_ = __builtin_elementwise_fma(za2, s2, dd_); \
    dd_ = __builtin_elementwise_fma(za3, s3, dd_); \
    float p = dd_.x + dd_.y; \
    p = qsum(p); \
    float ex = EXP2F(p); \
    float sm = rsum4(ex); \
    float wgt = ex * __builtin_amdgcn_rcpf(sm); \
    f32x2 w2 = {wgt, wgt}; \
    a0 = __builtin_elementwise_fma(w2, za0, a0); \
    a1 = __builtin_elementwise_fma(w2, za1, a1); \
    a2 = __builtin_elementwise_fma(w2, za2, a2); \
    a3 = __builtin_elementwise_fma(w2, za3, a3); }

#define PROC_G(ZU) { \
    f32x2 za0 = {unlo(ZU.x), unhi(ZU.x)}; \
    f32x2 za1 = {unlo(ZU.y), unhi(ZU.y)}; \
    f32x2 za2 = {unlo(ZU.z), unhi(ZU.z)}; \
    f32x2 za3 = {unlo(ZU.w), unhi(ZU.w)}; \
    PROC_R(za0, za1, za2, za3) }

__global__ __launch_bounds__(256) void route_layer(
    const int* __restrict__ rowStart, const int* __restrict__ eSrc,
    const unsigned short* __restrict__ XNh,
    unsigned short* __restrict__ XNOut, float* __restrict__ CT)
{
    int node = blockIdx.x * 4 + (threadIdx.x >> 6);  // NN % 4 == 0: always valid
    int lane = threadIdx.x & 63;
    int slot = lane >> 4;                           // 4 edge slots
    int h = lane & 15;                              // elems 8h..8h+7, channel h>>2
    int beg = rowStart[node], end = rowStart[node + 1];
    int deg = end - beg;
    const char* XNb = (const char*)XNh;

    // register-resident first 16 edges: slot handles r = slot + 4j, j=0..3
    f32x2 rz[4][4];
    #pragma unroll
    for (int j = 0; j < 4; ++j) {
        int r = slot + 4 * j;
        if (r < deg) {
            int src = eSrc[beg + r];
            uint4 v = *(const uint4*)(XNb + (src * 256 + h * 16));
            rz[j][0] = (f32x2){unlo(v.x), unhi(v.x)};
            rz[j][1] = (f32x2){unlo(v.y), unhi(v.y)};
            rz[j][2] = (f32x2){unlo(v.z), unhi(v.z)};
            rz[j][3] = (f32x2){unlo(v.w), unhi(v.w)};
        }
    }
    // residual xn row (same address for all 4 slots -> L1 broadcast)
    uint4 xr = *(const uint4*)(XNb + (node * 256 + h * 16));
    float x0 = unlo(xr.x), x1 = unhi(xr.x), x2 = unlo(xr.y), x3 = unhi(xr.y);
    float x4 = unlo(xr.z), x5 = unhi(xr.z), x6 = unlo(xr.w), x7 = unhi(xr.w);
    // initial s from xn (already channel-normalized), pre-scaled by log2e
    float tx = (x0 + x1 + x2 + x3) * LOG2E;
    float ty = (x4 + x5 + x6 + x7) * LOG2E;
    int sb = (lane & 48) | (4 * (h & 3));           // slot base + 4*(channel-pos)
    f32x2 s0, s1, s2, s3;
    s0.x = __shfl(tx, sb);     s0.y = __shfl(ty, sb);
    s1.x = __shfl(tx, sb + 1); s1.y = __shfl(ty, sb + 1);
    s2.x = __shfl(tx, sb + 2); s2.y = __shfl(ty, sb + 2);
    s3.x = __shfl(tx, sb + 3); s3.y = __shfl(ty, sb + 3);

    f32x2 a0, a1, a2, a3;
    #pragma unroll
    for (int iter = 0; iter < 3; ++iter) {
        if (slot == 0) {
            a0 = (f32x2){x0, x1}; a1 = (f32x2){x2, x3};
            a2 = (f32x2){x4, x5}; a3 = (f32x2){x6, x7};
        } else {
            a0 = (f32x2){0.f, 0.f}; a1 = a0; a2 = a0; a3 = a0;
        }
        // register-resident edges (deg<=16 common case: entire loop in regs)
        #pragma unroll
        for (int j = 0; j < 4; ++j) {
            if (slot + 4 * j < deg) PROC_R(rz[j][0], rz[j][1], rz[j][2], rz[j][3]);
        }
        // overflow edges straight from global (L2-resident)
        for (int i = 16 + slot; i < deg; i += 4) {
            uint4 zu = *(const uint4*)(XNb + (eSrc[beg + i] * 256 + h * 16));
            PROC_G(zu);
        }
        // combine 4 slots -> every lane holds full c[8h..8h+7]
        a0.x += __shfl_xor(a0.x, 16); a0.x += __shfl_xor(a0.x, 32);
        a0.y += __shfl_xor(a0.y, 16); a0.y += __shfl_xor(a0.y, 32);
        a1.x += __shfl_xor(a1.x, 16); a1.x += __shfl_xor(a1.x, 32);
        a1.y += __shfl_xor(a1.y, 16); a1.y += __shfl_xor(a1.y, 32);
        a2.x += __shfl_xor(a2.x, 16); a2.x += __shfl_xor(a2.x, 32);
        a2.y += __shfl_xor(a2.y, 16); a2.y += __shfl_xor(a2.y, 32);
        a3.x += __shfl_xor(a3.x, 16); a3.x += __shfl_xor(a3.x, 32);
        a3.y += __shfl_xor(a3.y, 16); a3.y += __shfl_xor(a3.y, 32);
        if (iter < 2) {
            // normalize in-register, derive next s (log2e folded), redistribute
            f32x2 q = a0 * a0;
            q = __builtin_elementwise_fma(a1, a1, q);
            q = __builtin_elementwise_fma(a2, a2, q);
            q = __builtin_elementwise_fma(a3, a3, q);
            float ssq = qsum(q.x + q.y);
            float scl = LOG2E / fmaxf(sqrtf(ssq), 1e-12f);
            tx = (a0.x + a0.y + a1.x + a1.y) * scl;
            ty = (a2.x + a2.y + a3.x + a3.y) * scl;
            s0.x = __shfl(tx, sb);     s0.y = __shfl(ty, sb);
            s1.x = __shfl(tx, sb + 1); s1.y = __shfl(ty, sb + 1);
            s2.x = __shfl(tx, sb + 2); s2.y = __shfl(ty, sb + 2);
            s3.x = __shfl(tx, sb + 3); s3.y = __shfl(ty, sb + 3);
        }
    }
    // epilogue
    if (XNOut) {   // layer 1: write channel-normalized bf16 (next layer's xn)
        f32x2 q = a0 * a0;
        q = __builtin_elementwise_fma(a1, a1, q);
        q = __builtin_elementwise_fma(a2, a2, q);
        q = __builtin_elementwise_fma(a3, a3, q);
        float ssq = qsum(q.x + q.y);
        float scale = 1.0f / fmaxf(sqrtf(ssq), 1e-12f);
        if (slot == 0) {
            uint4 pk;
            pk.x = pack2(a0.x * scale, a0.y * scale);
            pk.y = pack2(a1.x * scale, a1.y * scale);
            pk.z = pack2(a2.x * scale, a2.y * scale);
            pk.w = pack2(a3.x * scale, a3.y * scale);
            *(uint4*)((char*)XNOut + (node * 256 + h * 16)) = pk;
        }
    }
    if (CT && slot == 0) {   // layer 2: raw fp32 x
        float4* cp = (float4*)(CT + (node * 128 + 8 * h));
        cp[0] = make_float4(a0.x, a0.y, a1.x, a1.y);
        cp[1] = make_float4(a2.x, a2.y, a3.x, a3.y);
    }
}

extern "C" void kernel_launch(void* const* d_in, const int* in_sizes, int n_in,
                              void* d_out, int out_size, void* d_ws, size_t ws_size,
                              hipStream_t stream) {
    const void* feat  = d_in[0];
    const void* ei    = d_in[1];
    const void* lin_w = d_in[2];
    const void* lin_b = d_in[3];
    const void* mlp_w = d_in[4];
    const void* mlp_b = d_in[5];
    float* out = (float*)d_out;               // [out(N,128) | x(N,128)] fp32

    const int m = in_sizes[1] / 2;            // 800000 edges

    // ---- workspace layout ----
    char* wsB = (char*)d_ws;
    int*   flags = (int*)wsB;                                  // 256 B slot
    unsigned short* XH1 = (unsigned short*)(wsB + 256);        // NN*128 bf16
    unsigned short* XH2 = XH1 + ND;                            // NN*128 bf16
    int*   srcA  = (int*)(XH2 + ND);                           // m
    int*   trgA  = srcA + m;                                   // m
    int*   eSrc  = trgA + m;                                   // m
    int*   deg   = eSrc + m;                                   // NN
    int*   rowStart = deg + NN;                                // NN+1
    int*   cursor   = rowStart + NN + 1;                       // NN
    int*   blkSum   = cursor + NN;                             // 64
    int*   blkOff   = blkSum + 64;                             // 64
    float* W1f      = (float*)(blkOff + 64);                   // 16384
    float* B1f      = W1f + 16384;                             // 128
    float* W2f      = B1f + 128;                               // 16384
    float* B2f      = W2f + 16384;                             // 128

    hipMemsetAsync(flags, 0, 8, stream);
    hipMemsetAsync(deg, 0, NN * sizeof(int), stream);
    detect<<<1, 256, 0, stream>>>((const unsigned short*)feat, (const unsigned int*)ei, flags);
    prep_w<<<64, 256, 0, stream>>>(lin_w, lin_b, mlp_w, mlp_b, W1f, B1f, W2f, B2f, flags);

    const int edgeBlocks = (m + 255) / 256;
    conv_hist<<<edgeBlocks, 256, 0, stream>>>(ei, srcA, trgA, deg, m, flags);
    scan1<<<SCAN_B, 256, 0, stream>>>(deg, rowStart, blkSum);
    scan2<<<1, 64, 0, stream>>>(blkSum, blkOff, rowStart, m);
    scan3<<<SCAN_B, 256, 0, stream>>>(rowStart, blkOff, cursor);
    scatter_csr<<<edgeBlocks, 256, 0, stream>>>(srcA, trgA, cursor, eSrc, m);

    const int gemmBlocks = (NN + 31) / 32;
    const int nodeBlocks = NN / 4;            // NN % 4 == 0

    // gemm1 + fused normalize: feat -> XH1 (bf16)
    gemm_norm<<<gemmBlocks, 256, 0, stream>>>(feat, W1f, B1f, XH1, flags);

    // layer 1: all 3 routing iterations fused; writes normalized bf16 XH2
    route_layer<<<nodeBlocks, 256, 0, stream>>>(rowStart, eSrc, XH1, XH2, nullptr);
    // layer 2: writes raw fp32 x -> out+ND
    route_layer<<<nodeBlocks, 256, 0, stream>>>(rowStart, eSrc, XH2, nullptr, out + ND);

    // out = x @ mlp_w + mlp_b, reading x straight from out+ND
    gemm_plain<<<gemmBlocks, 256, 0, stream>>>(out + ND, W2f, B2f, out);
}

// Round 4
// 407.399 us; speedup vs baseline: 1.0262x; 1.0262x over previous
//
#include <hip/hip_runtime.h>

#define NN 50000
#define ND (NN * 128)
#define SCAN_B 49   // ceil(NN / 1024)
#define CAP 16      // LDS-cached neighbor rows per node (16KB/block -> comfortable 8 blocks/CU)
#define LOG2E 1.4426950408889634f

typedef float f32x2 __attribute__((ext_vector_type(2)));

#if defined(__has_builtin)
#  if __has_builtin(__builtin_amdgcn_exp2f)
#    define EXP2F(x) __builtin_amdgcn_exp2f(x)
#  else
#    define EXP2F(x) exp2f(x)
#  endif
#else
#  define EXP2F(x) exp2f(x)
#endif

__device__ __forceinline__ float b2f(unsigned short u) {
    union { unsigned int i; float f; } v; v.i = ((unsigned int)u) << 16; return v.f;
}
__device__ __forceinline__ unsigned short f2b(float f) {      // RNE bf16 pack
    union { float f; unsigned int i; } v; v.f = f;
    return (unsigned short)((v.i + 0x7fffu + ((v.i >> 16) & 1u)) >> 16);
}
__device__ __forceinline__ unsigned int pack2(float lo, float hi) {
    return (unsigned int)f2b(lo) | ((unsigned int)f2b(hi) << 16);
}
__device__ __forceinline__ float unlo(unsigned int u) { return __uint_as_float(u << 16); }
__device__ __forceinline__ float unhi(unsigned int u) { return __uint_as_float(u & 0xFFFF0000u); }
__device__ __forceinline__ int clampi(int i, int lo, int hi) { return max(lo, min(i, hi)); }

// DPP lane ops (VALU pipe, no LDS traffic). All patterns stay within a 16-lane row,
// i.e. within one slot -> safe under slot-level divergence.
template<int CTRL>
__device__ __forceinline__ float dmov(float v) {
    return __int_as_float(__builtin_amdgcn_update_dpp(0, __float_as_int(v), CTRL, 0xF, 0xF, true));
}
template<int CTRL> __device__ __forceinline__ float dadd(float v) { return v + dmov<CTRL>(v); }
__device__ __forceinline__ float qsum(float v) { v = dadd<0xB1>(v); v = dadd<0x4E>(v); return v; }
__device__ __forceinline__ float rsum4(float v) { v = dadd<0x124>(v); v = dadd<0x128>(v); return v; }

// ---- dtype detection: flags[0]=1 if floats fp32; flags[1]=1 if edges int32 ----
__global__ __launch_bounds__(256) void detect(
    const unsigned short* __restrict__ feat_u, const unsigned int* __restrict__ ei_u,
    int* __restrict__ flags)
{
    int tid = threadIdx.x;
    int f32hit = 0;
    for (int i = tid; i < 8192; i += 256) {
        unsigned e = (feat_u[i] >> 7) & 0xFFu;
        if (e >= 0xC0u) f32hit = 1;
    }
    int i32hit = 0;
    for (int i = tid; i < 4096; i += 256)
        if (ei_u[2 * i + 1] != 0u) i32hit = 1;
    if (f32hit) atomicOr(&flags[0], 1);
    if (i32hit) atomicOr(&flags[1], 1);
}

// ---- one-time W/bias -> fp32 workspace (removes per-block convert in GEMMs) ----
__global__ __launch_bounds__(256) void prep_w(
    const void* __restrict__ W1, const void* __restrict__ B1,
    const void* __restrict__ W2, const void* __restrict__ B2,
    float* __restrict__ w1o, float* __restrict__ b1o,
    float* __restrict__ w2o, float* __restrict__ b2o,
    const int* __restrict__ flags)
{
    bool isF32 = flags[0] != 0;
    int idx = blockIdx.x * 256 + threadIdx.x;
    if (idx < 16384) {
        if (isF32) { w1o[idx] = ((const float*)W1)[idx]; w2o[idx] = ((const float*)W2)[idx]; }
        else {
            w1o[idx] = b2f(((const unsigned short*)W1)[idx]);
            w2o[idx] = b2f(((const unsigned short*)W2)[idx]);
        }
    }
    if (idx < 128) {
        if (isF32) { b1o[idx] = ((const float*)B1)[idx]; b2o[idx] = ((const float*)B2)[idx]; }
        else {
            b1o[idx] = b2f(((const unsigned short*)B1)[idx]);
            b2o[idx] = b2f(((const unsigned short*)B2)[idx]);
        }
    }
}

// ---- extract int32 src/trg + degree histogram ----
__global__ __launch_bounds__(256) void conv_hist(
    const void* __restrict__ eiRaw, int* __restrict__ srcA, int* __restrict__ trgA,
    int* __restrict__ deg, int m, const int* __restrict__ flags)
{
    int e = blockIdx.x * 256 + threadIdx.x;
    if (e >= m) return;
    int src, trg;
    if (flags[1]) { const int* p = (const int*)eiRaw; src = p[e]; trg = p[m + e]; }
    else { const long long* p = (const long long*)eiRaw; src = (int)p[e]; trg = (int)p[m + e]; }
    src = clampi(src, 0, NN - 1);
    trg = clampi(trg, 0, NN - 1);
    srcA[e] = src; trgA[e] = trg;
    atomicAdd(&deg[trg], 1);
}

// ---- exclusive scan of deg[NN] -> rowStart[NN+1] ----
__global__ __launch_bounds__(256) void scan1(
    const int* __restrict__ deg, int* __restrict__ rowStart, int* __restrict__ blkSum)
{
    __shared__ int lds[256];
    int blk = blockIdx.x, tid = threadIdx.x;
    int base = blk * 1024 + tid * 4;
    int v[4]; int s = 0;
    #pragma unroll
    for (int j = 0; j < 4; ++j) { int idx = base + j; v[j] = (idx < NN) ? deg[idx] : 0; s += v[j]; }
    lds[tid] = s; __syncthreads();
    for (int off = 1; off < 256; off <<= 1) {
        int x = (tid >= off) ? lds[tid - off] : 0;
        __syncthreads();
        lds[tid] += x;
        __syncthreads();
    }
    int excl = lds[tid] - s;
    if (tid == 255) blkSum[blk] = lds[tid];
    int run = excl;
    #pragma unroll
    for (int j = 0; j < 4; ++j) { int idx = base + j; if (idx < NN) rowStart[idx] = run; run += v[j]; }
}
__global__ __launch_bounds__(64) void scan2(
    int* __restrict__ blkSum, int* __restrict__ blkOff, int* __restrict__ rowStart, int m)
{
    int lane = threadIdx.x;
    int orig = (lane < SCAN_B) ? blkSum[lane] : 0;
    int v = orig;
    for (int off = 1; off < 64; off <<= 1) {
        int x = __shfl_up(v, off);
        if (lane >= off) v += x;
    }
    if (lane < SCAN_B) blkOff[lane] = v - orig;
    if (lane == 0) rowStart[NN] = m;
}
// scan3 also seeds cursor (replaces the D2D memcpy dispatch)
__global__ __launch_bounds__(256) void scan3(
    int* __restrict__ rowStart, const int* __restrict__ blkOff, int* __restrict__ cursor)
{
    int base = blockIdx.x * 1024 + threadIdx.x * 4;
    int off = blkOff[blockIdx.x];
    #pragma unroll
    for (int j = 0; j < 4; ++j) {
        int idx = base + j;
        if (idx < NN) { int v = rowStart[idx] + off; rowStart[idx] = v; cursor[idx] = v; }
    }
}

// ---- scatter edges into CSR bins ----
__global__ __launch_bounds__(256) void scatter_csr(
    const int* __restrict__ srcA, const int* __restrict__ trgA,
    int* __restrict__ cursor, int* __restrict__ eSrc, int m)
{
    int e = blockIdx.x * 256 + threadIdx.x;
    if (e >= m) return;
    int pos = atomicAdd(&cursor[trgA[e]], 1);
    eSrc[pos] = srcA[e];
}

// ---- GEMM1: XNh(bf16) = channel_normalize(feat @ W + b). W/bias fp32 (prepped).
// W streamed from global (L1/L2-cached, coalesced 512B panels). LDS = As only (16KB).
__global__ __launch_bounds__(256) void gemm_norm(
    const void* __restrict__ A, const float* __restrict__ W, const float* __restrict__ bias,
    unsigned short* __restrict__ XNh, const int* __restrict__ flags)
{
    __shared__ float As[32 * 128];
    int tid = threadIdx.x;
    int cg = tid & 31;                // cols 4cg..4cg+3
    int rg = tid >> 5;                // rows rg*4..rg*4+3 (of 32)
    int rowBase = blockIdx.x * 32;
    bool isF32 = flags[0] != 0;

    #pragma unroll
    for (int r = 0; r < 4; ++r) {
        int lrow = r * 8 + rg;
        int row = rowBase + lrow;
        float4 v = make_float4(0.f, 0.f, 0.f, 0.f);
        if (row < NN) {
            if (isF32) v = *(const float4*)&((const float*)A)[(long)row * 128 + cg * 4];
            else {
                ushort4 u = *(const ushort4*)&((const unsigned short*)A)[(long)row * 128 + cg * 4];
                v = make_float4(b2f(u.x), b2f(u.y), b2f(u.z), b2f(u.w));
            }
        }
        *(float4*)&As[lrow * 128 + cg * 4] = v;
    }
    float4 bb = *(const float4*)&bias[cg * 4];
    __syncthreads();

    float acc[4][4];
    #pragma unroll
    for (int i = 0; i < 4; ++i) { acc[i][0]=bb.x; acc[i][1]=bb.y; acc[i][2]=bb.z; acc[i][3]=bb.w; }

    #pragma unroll 2
    for (int k4 = 0; k4 < 32; ++k4) {
        float4 w[4], av[4];
        #pragma unroll
        for (int j = 0; j < 4; ++j)
            w[j] = *(const float4*)&W[(k4 * 4 + j) * 128 + cg * 4];
        #pragma unroll
        for (int i = 0; i < 4; ++i)
            av[i] = *(const float4*)&As[(rg * 4 + i) * 128 + k4 * 4];
        #pragma unroll
        for (int i = 0; i < 4; ++i) {
            const float a0 = av[i].x, a1 = av[i].y, a2 = av[i].z, a3 = av[i].w;
            acc[i][0] = fmaf(a0, w[0].x, fmaf(a1, w[1].x, fmaf(a2, w[2].x, fmaf(a3, w[3].x, acc[i][0]))));
            acc[i][1] = fmaf(a0, w[0].y, fmaf(a1, w[1].y, fmaf(a2, w[2].y, fmaf(a3, w[3].y, acc[i][1]))));
            acc[i][2] = fmaf(a0, w[0].z, fmaf(a1, w[1].z, fmaf(a2, w[2].z, fmaf(a3, w[3].z, acc[i][2]))));
            acc[i][3] = fmaf(a0, w[0].w, fmaf(a1, w[1].w, fmaf(a2, w[2].w, fmaf(a3, w[3].w, acc[i][3]))));
        }
    }
    #pragma unroll
    for (int i = 0; i < 4; ++i) {
        int row = rowBase + rg * 4 + i;
        float lss = acc[i][0]*acc[i][0] + acc[i][1]*acc[i][1] + acc[i][2]*acc[i][2] + acc[i][3]*acc[i][3];
        lss += __shfl_xor(lss, 1);
        lss += __shfl_xor(lss, 2);
        lss += __shfl_xor(lss, 4);
        float scale = 1.0f / fmaxf(sqrtf(lss), 1e-12f);
        if (row < NN) {
            float4 o; o.x = acc[i][0]*scale; o.y = acc[i][1]*scale; o.z = acc[i][2]*scale; o.w = acc[i][3]*scale;
            uint2 pk; pk.x = pack2(o.x, o.y); pk.y = pack2(o.z, o.w);
            *(uint2*)((char*)XNh + (long)row * 256 + cg * 8) = pk;
        }
    }
}

// ---- GEMM2: Out = A @ W + b (A fp32, W/bias fp32 prepped) ----
__global__ __launch_bounds__(256) void gemm_plain(
    const float* __restrict__ A, const float* __restrict__ W, const float* __restrict__ bias,
    float* __restrict__ Out)
{
    __shared__ float As[32 * 128];
    int tid = threadIdx.x;
    int cg = tid & 31;
    int rg = tid >> 5;
    int rowBase = blockIdx.x * 32;

    #pragma unroll
    for (int r = 0; r < 4; ++r) {
        int lrow = r * 8 + rg;
        int row = rowBase + lrow;
        float4 v = make_float4(0.f, 0.f, 0.f, 0.f);
        if (row < NN) v = *(const float4*)&A[(long)row * 128 + cg * 4];
        *(float4*)&As[lrow * 128 + cg * 4] = v;
    }
    float4 bb = *(const float4*)&bias[cg * 4];
    __syncthreads();

    float acc[4][4];
    #pragma unroll
    for (int i = 0; i < 4; ++i) { acc[i][0]=bb.x; acc[i][1]=bb.y; acc[i][2]=bb.z; acc[i][3]=bb.w; }

    #pragma unroll 2
    for (int k4 = 0; k4 < 32; ++k4) {
        float4 w[4], av[4];
        #pragma unroll
        for (int j = 0; j < 4; ++j)
            w[j] = *(const float4*)&W[(k4 * 4 + j) * 128 + cg * 4];
        #pragma unroll
        for (int i = 0; i < 4; ++i)
            av[i] = *(const float4*)&As[(rg * 4 + i) * 128 + k4 * 4];
        #pragma unroll
        for (int i = 0; i < 4; ++i) {
            const float a0 = av[i].x, a1 = av[i].y, a2 = av[i].z, a3 = av[i].w;
            acc[i][0] = fmaf(a0, w[0].x, fmaf(a1, w[1].x, fmaf(a2, w[2].x, fmaf(a3, w[3].x, acc[i][0]))));
            acc[i][1] = fmaf(a0, w[0].y, fmaf(a1, w[1].y, fmaf(a2, w[2].y, fmaf(a3, w[3].y, acc[i][1]))));
            acc[i][2] = fmaf(a0, w[0].z, fmaf(a1, w[1].z, fmaf(a2, w[2].z, fmaf(a3, w[3].z, acc[i][2]))));
            acc[i][3] = fmaf(a0, w[0].w, fmaf(a1, w[1].w, fmaf(a2, w[2].w, fmaf(a3, w[3].w, acc[i][3]))));
        }
    }
    #pragma unroll
    for (int i = 0; i < 4; ++i) {
        int row = rowBase + rg * 4 + i;
        if (row < NN) {
            float4 o; o.x = acc[i][0]; o.y = acc[i][1]; o.z = acc[i][2]; o.w = acc[i][3];
            *(float4*)&Out[(long)row * 128 + cg * 4] = o;
        }
    }
}

// ---- fused per-layer routing: 1 wave/node, all 3 iterations, z staged in LDS ----
// v5: v3 LDS structure (v4's register-resident z spilled to AGPRs -> reverted).
// New: dual accumulators (even edges -> b*, odd -> a*) break the cross-edge
// accumulate dependency so the two unrolled softmax chains are fully independent.
// CAP 16 (16KB/block): guarantees the 8-block/CU ceiling with LDS slack.
#define PROC4(ZU, c0, c1, c2, c3) { \
    f32x2 za0 = {unlo(ZU.x), unhi(ZU.x)}; \
    f32x2 za1 = {unlo(ZU.y), unhi(ZU.y)}; \
    f32x2 za2 = {unlo(ZU.z), unhi(ZU.z)}; \
    f32x2 za3 = {unlo(ZU.w), unhi(ZU.w)}; \
    f32x2 dd_ = za0 * s0; \
    dd_ = __builtin_elementwise_fma(za1, s1, dd_); \
    dd_ = __builtin_elementwise_fma(za2, s2, dd_); \
    dd_ = __builtin_elementwise_fma(za3, s3, dd_); \
    float p = dd_.x + dd_.y; \
    p = qsum(p); \
    float ex = EXP2F(p); \
    float sm = rsum4(ex); \
    float wgt = ex * __builtin_amdgcn_rcpf(sm); \
    f32x2 w2 = {wgt, wgt}; \
    c0 = __builtin_elementwise_fma(w2, za0, c0); \
    c1 = __builtin_elementwise_fma(w2, za1, c1); \
    c2 = __builtin_elementwise_fma(w2, za2, c2); \
    c3 = __builtin_elementwise_fma(w2, za3, c3); }

__global__ __launch_bounds__(256) void route_layer(
    const int* __restrict__ rowStart, const int* __restrict__ eSrc,
    const unsigned short* __restrict__ XNh,
    unsigned short* __restrict__ XNOut, float* __restrict__ CT)
{
    __shared__ unsigned short zbuf[4][CAP * 128];   // 16 KB
    int w = threadIdx.x >> 6;
    int node = blockIdx.x * 4 + w;                  // NN % 4 == 0: always valid
    int lane = threadIdx.x & 63;
    int slot = lane >> 4;                           // 4 edge slots
    int h = lane & 15;                              // elems 8h..8h+7, channel h>>2
    int beg = rowStart[node], end = rowStart[node + 1];
    int deg = end - beg;
    int degL = min(deg, CAP);
    const char* XNb = (const char*)XNh;

    // stage neighbor z rows into this wave's LDS slab: 16 lanes per row, 4 rows/pass
    for (int r = slot; r < degL; r += 4) {
        int src = eSrc[beg + r];
        uint4 v = *(const uint4*)(XNb + (src * 256 + h * 16));
        *(uint4*)&zbuf[w][r * 128 + h * 8] = v;
    }
    // residual xn row (same address for all 4 slots -> L1 broadcast)
    uint4 xr = *(const uint4*)(XNb + (node * 256 + h * 16));
    float x0 = unlo(xr.x), x1 = unhi(xr.x), x2 = unlo(xr.y), x3 = unhi(xr.y);
    float x4 = unlo(xr.z), x5 = unhi(xr.z), x6 = unlo(xr.w), x7 = unhi(xr.w);
    // initial s from xn (already channel-normalized), pre-scaled by log2e
    float tx = (x0 + x1 + x2 + x3) * LOG2E;
    float ty = (x4 + x5 + x6 + x7) * LOG2E;
    int sb = (lane & 48) | (4 * (h & 3));           // slot base + 4*(channel-pos)
    f32x2 s0, s1, s2, s3;
    s0.x = __shfl(tx, sb);     s0.y = __shfl(ty, sb);
    s1.x = __shfl(tx, sb + 1); s1.y = __shfl(ty, sb + 1);
    s2.x = __shfl(tx, sb + 2); s2.y = __shfl(ty, sb + 2);
    s3.x = __shfl(tx, sb + 3); s3.y = __shfl(ty, sb + 3);
    // zbuf is per-wave: only intra-wave ordering of ds_write -> ds_read is needed.
    asm volatile("s_waitcnt lgkmcnt(0)" ::: "memory");

    f32x2 a0, a1, a2, a3;
    #pragma unroll
    for (int iter = 0; iter < 3; ++iter) {
        if (slot == 0) {
            a0 = (f32x2){x0, x1}; a1 = (f32x2){x2, x3};
            a2 = (f32x2){x4, x5}; a3 = (f32x2){x6, x7};
        } else {
            a0 = (f32x2){0.f, 0.f}; a1 = a0; a2 = a0; a3 = a0;
        }
        f32x2 b0 = (f32x2){0.f, 0.f}, b1 = b0, b2 = b0, b3 = b0;  // secondary acc
        // LDS-resident edges: 2x unrolled, independent chains via dual accumulators
        int i = slot;
        for (; i + 4 < degL; i += 8) {
            uint4 zu0 = *(const uint4*)&zbuf[w][i * 128 + h * 8];
            uint4 zu1 = *(const uint4*)&zbuf[w][(i + 4) * 128 + h * 8];
            PROC4(zu0, a0, a1, a2, a3);
            PROC4(zu1, b0, b1, b2, b3);
        }
        if (i < degL) {
            uint4 zu = *(const uint4*)&zbuf[w][i * 128 + h * 8];
            PROC4(zu, a0, a1, a2, a3);
        }
        // rare overflow edges straight from global (L2-resident)
        for (int j = CAP + slot; j < deg; j += 4) {
            uint4 zu = *(const uint4*)(XNb + (eSrc[beg + j] * 256 + h * 16));
            PROC4(zu, b0, b1, b2, b3);
        }
        // merge secondary accumulator
        a0 += b0; a1 += b1; a2 += b2; a3 += b3;
        // combine 4 slots -> every lane holds full c[8h..8h+7]
        a0.x += __shfl_xor(a0.x, 16); a0.x += __shfl_xor(a0.x, 32);
        a0.y += __shfl_xor(a0.y, 16); a0.y += __shfl_xor(a0.y, 32);
        a1.x += __shfl_xor(a1.x, 16); a1.x += __shfl_xor(a1.x, 32);
        a1.y += __shfl_xor(a1.y, 16); a1.y += __shfl_xor(a1.y, 32);
        a2.x += __shfl_xor(a2.x, 16); a2.x += __shfl_xor(a2.x, 32);
        a2.y += __shfl_xor(a2.y, 16); a2.y += __shfl_xor(a2.y, 32);
        a3.x += __shfl_xor(a3.x, 16); a3.x += __shfl_xor(a3.x, 32);
        a3.y += __shfl_xor(a3.y, 16); a3.y += __shfl_xor(a3.y, 32);
        if (iter < 2) {
            // normalize in-register, derive next s (log2e folded), redistribute
            f32x2 q = a0 * a0;
            q = __builtin_elementwise_fma(a1, a1, q);
            q = __builtin_elementwise_fma(a2, a2, q);
            q = __builtin_elementwise_fma(a3, a3, q);
            float ssq = qsum(q.x + q.y);
            float scl = LOG2E / fmaxf(sqrtf(ssq), 1e-12f);
            tx = (a0.x + a0.y + a1.x + a1.y) * scl;
            ty = (a2.x + a2.y + a3.x + a3.y) * scl;
            s0.x = __shfl(tx, sb);     s0.y = __shfl(ty, sb);
            s1.x = __shfl(tx, sb + 1); s1.y = __shfl(ty, sb + 1);
            s2.x = __shfl(tx, sb + 2); s2.y = __shfl(ty, sb + 2);
            s3.x = __shfl(tx, sb + 3); s3.y = __shfl(ty, sb + 3);
        }
    }
    // epilogue
    if (XNOut) {   // layer 1: write channel-normalized bf16 (next layer's xn)
        f32x2 q = a0 * a0;
        q = __builtin_elementwise_fma(a1, a1, q);
        q = __builtin_elementwise_fma(a2, a2, q);
        q = __builtin_elementwise_fma(a3, a3, q);
        float ssq = qsum(q.x + q.y);
        float scale = 1.0f / fmaxf(sqrtf(ssq), 1e-12f);
        if (slot == 0) {
            uint4 pk;
            pk.x = pack2(a0.x * scale, a0.y * scale);
            pk.y = pack2(a1.x * scale, a1.y * scale);
            pk.z = pack2(a2.x * scale, a2.y * scale);
            pk.w = pack2(a3.x * scale, a3.y * scale);
            *(uint4*)((char*)XNOut + (node * 256 + h * 16)) = pk;
        }
    }
    if (CT && slot == 0) {   // layer 2: raw fp32 x
        float4* cp = (float4*)(CT + (node * 128 + 8 * h));
        cp[0] = make_float4(a0.x, a0.y, a1.x, a1.y);
        cp[1] = make_float4(a2.x, a2.y, a3.x, a3.y);
    }
}

extern "C" void kernel_launch(void* const* d_in, const int* in_sizes, int n_in,
                              void* d_out, int out_size, void* d_ws, size_t ws_size,
                              hipStream_t stream) {
    const void* feat  = d_in[0];
    const void* ei    = d_in[1];
    const void* lin_w = d_in[2];
    const void* lin_b = d_in[3];
    const void* mlp_w = d_in[4];
    const void* mlp_b = d_in[5];
    float* out = (float*)d_out;               // [out(N,128) | x(N,128)] fp32

    const int m = in_sizes[1] / 2;            // 800000 edges

    // ---- workspace layout ----
    char* wsB = (char*)d_ws;
    int*   flags = (int*)wsB;                                  // 256 B slot
    unsigned short* XH1 = (unsigned short*)(wsB + 256);        // NN*128 bf16
    unsigned short* XH2 = XH1 + ND;                            // NN*128 bf16
    int*   srcA  = (int*)(XH2 + ND);                           // m
    int*   trgA  = srcA + m;                                   // m
    int*   eSrc  = trgA + m;                                   // m
    int*   deg   = eSrc + m;                                   // NN
    int*   rowStart = deg + NN;                                // NN+1
    int*   cursor   = rowStart + NN + 1;                       // NN
    int*   blkSum   = cursor + NN;                             // 64
    int*   blkOff   = blkSum + 64;                             // 64
    float* W1f      = (float*)(blkOff + 64);                   // 16384
    float* B1f      = W1f + 16384;                             // 128
    float* W2f      = B1f + 128;                               // 16384
    float* B2f      = W2f + 16384;                             // 128

    hipMemsetAsync(flags, 0, 8, stream);
    hipMemsetAsync(deg, 0, NN * sizeof(int), stream);
    detect<<<1, 256, 0, stream>>>((const unsigned short*)feat, (const unsigned int*)ei, flags);
    prep_w<<<64, 256, 0, stream>>>(lin_w, lin_b, mlp_w, mlp_b, W1f, B1f, W2f, B2f, flags);

    const int edgeBlocks = (m + 255) / 256;
    conv_hist<<<edgeBlocks, 256, 0, stream>>>(ei, srcA, trgA, deg, m, flags);
    scan1<<<SCAN_B, 256, 0, stream>>>(deg, rowStart, blkSum);
    scan2<<<1, 64, 0, stream>>>(blkSum, blkOff, rowStart, m);
    scan3<<<SCAN_B, 256, 0, stream>>>(rowStart, blkOff, cursor);
    scatter_csr<<<edgeBlocks, 256, 0, stream>>>(srcA, trgA, cursor, eSrc, m);

    const int gemmBlocks = (NN + 31) / 32;
    const int nodeBlocks = NN / 4;            // NN % 4 == 0

    // gemm1 + fused normalize: feat -> XH1 (bf16)
    gemm_norm<<<gemmBlocks, 256, 0, stream>>>(feat, W1f, B1f, XH1, flags);

    // layer 1: all 3 routing iterations fused; writes normalized bf16 XH2
    route_layer<<<nodeBlocks, 256, 0, stream>>>(rowStart, eSrc, XH1, XH2, nullptr);
    // layer 2: writes raw fp32 x -> out+ND
    route_layer<<<nodeBlocks, 256, 0, stream>>>(rowStart, eSrc, XH2, nullptr, out + ND);

    // out = x @ mlp_w + mlp_b, reading x straight from out+ND
    gemm_plain<<<gemmBlocks, 256, 0, stream>>>(out + ND, W2f, B2f, out);
}

// Round 5
// 394.458 us; speedup vs baseline: 1.0599x; 1.0328x over previous
//
#include <hip/hip_runtime.h>

#define NN 50000
#define ND (NN * 128)
#define SCAN_B 49   // ceil(NN / 1024)
#define CAP 20      // LDS-cached neighbor rows per node (best measured: v3 @ 75.6us)
#define LOG2E 1.4426950408889634f

typedef float f32x2 __attribute__((ext_vector_type(2)));

#if defined(__has_builtin)
#  if __has_builtin(__builtin_amdgcn_exp2f)
#    define EXP2F(x) __builtin_amdgcn_exp2f(x)
#  else
#    define EXP2F(x) exp2f(x)
#  endif
#else
#  define EXP2F(x) exp2f(x)
#endif

__device__ __forceinline__ float b2f(unsigned short u) {
    union { unsigned int i; float f; } v; v.i = ((unsigned int)u) << 16; return v.f;
}
__device__ __forceinline__ unsigned short f2b(float f) {      // RNE bf16 pack
    union { float f; unsigned int i; } v; v.f = f;
    return (unsigned short)((v.i + 0x7fffu + ((v.i >> 16) & 1u)) >> 16);
}
__device__ __forceinline__ unsigned int pack2(float lo, float hi) {
    return (unsigned int)f2b(lo) | ((unsigned int)f2b(hi) << 16);
}
__device__ __forceinline__ float unlo(unsigned int u) { return __uint_as_float(u << 16); }
__device__ __forceinline__ float unhi(unsigned int u) { return __uint_as_float(u & 0xFFFF0000u); }
__device__ __forceinline__ int clampi(int i, int lo, int hi) { return max(lo, min(i, hi)); }

// DPP lane ops (VALU pipe, no LDS traffic). All patterns stay within a 16-lane row.
template<int CTRL>
__device__ __forceinline__ float dmov(float v) {
    return __int_as_float(__builtin_amdgcn_update_dpp(0, __float_as_int(v), CTRL, 0xF, 0xF, true));
}
template<int CTRL> __device__ __forceinline__ float dadd(float v) { return v + dmov<CTRL>(v); }
__device__ __forceinline__ float qsum(float v) { v = dadd<0xB1>(v); v = dadd<0x4E>(v); return v; }
__device__ __forceinline__ float rsum4(float v) { v = dadd<0x124>(v); v = dadd<0x128>(v); return v; }

// ---- dtype detection: flags[0]=1 if floats fp32; flags[1]=1 if edges int32 ----
__global__ __launch_bounds__(256) void detect(
    const unsigned short* __restrict__ feat_u, const unsigned int* __restrict__ ei_u,
    int* __restrict__ flags)
{
    int tid = threadIdx.x;
    int f32hit = 0;
    for (int i = tid; i < 8192; i += 256) {
        unsigned e = (feat_u[i] >> 7) & 0xFFu;
        if (e >= 0xC0u) f32hit = 1;
    }
    int i32hit = 0;
    for (int i = tid; i < 4096; i += 256)
        if (ei_u[2 * i + 1] != 0u) i32hit = 1;
    if (f32hit) atomicOr(&flags[0], 1);
    if (i32hit) atomicOr(&flags[1], 1);
}

// ---- one-time W/bias -> fp32 workspace (removes per-block convert in GEMMs) ----
__global__ __launch_bounds__(256) void prep_w(
    const void* __restrict__ W1, const void* __restrict__ B1,
    const void* __restrict__ W2, const void* __restrict__ B2,
    float* __restrict__ w1o, float* __restrict__ b1o,
    float* __restrict__ w2o, float* __restrict__ b2o,
    const int* __restrict__ flags)
{
    bool isF32 = flags[0] != 0;
    int idx = blockIdx.x * 256 + threadIdx.x;
    if (idx < 16384) {
        if (isF32) { w1o[idx] = ((const float*)W1)[idx]; w2o[idx] = ((const float*)W2)[idx]; }
        else {
            w1o[idx] = b2f(((const unsigned short*)W1)[idx]);
            w2o[idx] = b2f(((const unsigned short*)W2)[idx]);
        }
    }
    if (idx < 128) {
        if (isF32) { b1o[idx] = ((const float*)B1)[idx]; b2o[idx] = ((const float*)B2)[idx]; }
        else {
            b1o[idx] = b2f(((const unsigned short*)B1)[idx]);
            b2o[idx] = b2f(((const unsigned short*)B2)[idx]);
        }
    }
}

// ---- degree histogram (reads trg half of raw edge list only) ----
__global__ __launch_bounds__(256) void conv_hist(
    const void* __restrict__ eiRaw, int* __restrict__ deg, int m,
    const int* __restrict__ flags)
{
    int e = blockIdx.x * 256 + threadIdx.x;
    if (e >= m) return;
    int trg;
    if (flags[1]) trg = ((const int*)eiRaw)[m + e];
    else          trg = (int)((const long long*)eiRaw)[m + e];
    trg = clampi(trg, 0, NN - 1);
    atomicAdd(&deg[trg], 1);
}

// ---- exclusive scan of deg[NN] -> rowStart[NN+1] ----
__global__ __launch_bounds__(256) void scan1(
    const int* __restrict__ deg, int* __restrict__ rowStart, int* __restrict__ blkSum)
{
    __shared__ int lds[256];
    int blk = blockIdx.x, tid = threadIdx.x;
    int base = blk * 1024 + tid * 4;
    int v[4]; int s = 0;
    #pragma unroll
    for (int j = 0; j < 4; ++j) { int idx = base + j; v[j] = (idx < NN) ? deg[idx] : 0; s += v[j]; }
    lds[tid] = s; __syncthreads();
    for (int off = 1; off < 256; off <<= 1) {
        int x = (tid >= off) ? lds[tid - off] : 0;
        __syncthreads();
        lds[tid] += x;
        __syncthreads();
    }
    int excl = lds[tid] - s;
    if (tid == 255) blkSum[blk] = lds[tid];
    int run = excl;
    #pragma unroll
    for (int j = 0; j < 4; ++j) { int idx = base + j; if (idx < NN) rowStart[idx] = run; run += v[j]; }
}
__global__ __launch_bounds__(64) void scan2(
    int* __restrict__ blkSum, int* __restrict__ blkOff, int* __restrict__ rowStart, int m)
{
    int lane = threadIdx.x;
    int orig = (lane < SCAN_B) ? blkSum[lane] : 0;
    int v = orig;
    for (int off = 1; off < 64; off <<= 1) {
        int x = __shfl_up(v, off);
        if (lane >= off) v += x;
    }
    if (lane < SCAN_B) blkOff[lane] = v - orig;
    if (lane == 0) rowStart[NN] = m;
}
// scan3 also seeds cursor (replaces the D2D memcpy dispatch)
__global__ __launch_bounds__(256) void scan3(
    int* __restrict__ rowStart, const int* __restrict__ blkOff, int* __restrict__ cursor)
{
    int base = blockIdx.x * 1024 + threadIdx.x * 4;
    int off = blkOff[blockIdx.x];
    #pragma unroll
    for (int j = 0; j < 4; ++j) {
        int idx = base + j;
        if (idx < NN) { int v = rowStart[idx] + off; rowStart[idx] = v; cursor[idx] = v; }
    }
}

// ---- scatter edges into CSR bins (re-reads raw edge list; no src/trg arrays) ----
__global__ __launch_bounds__(256) void scatter_csr(
    const void* __restrict__ eiRaw, int* __restrict__ cursor, int* __restrict__ eSrc,
    int m, const int* __restrict__ flags)
{
    int e = blockIdx.x * 256 + threadIdx.x;
    if (e >= m) return;
    int src, trg;
    if (flags[1]) { const int* p = (const int*)eiRaw; src = p[e]; trg = p[m + e]; }
    else { const long long* p = (const long long*)eiRaw; src = (int)p[e]; trg = (int)p[m + e]; }
    src = clampi(src, 0, NN - 1);
    trg = clampi(trg, 0, NN - 1);
    int pos = atomicAdd(&cursor[trg], 1);
    eSrc[pos] = src;
}

// ---- GEMM1: XNh(bf16) = channel_normalize(feat @ W + b). W/bias fp32 (prepped).
__global__ __launch_bounds__(256) void gemm_norm(
    const void* __restrict__ A, const float* __restrict__ W, const float* __restrict__ bias,
    unsigned short* __restrict__ XNh, const int* __restrict__ flags)
{
    __shared__ float As[32 * 128];
    int tid = threadIdx.x;
    int cg = tid & 31;                // cols 4cg..4cg+3
    int rg = tid >> 5;                // rows rg*4..rg*4+3 (of 32)
    int rowBase = blockIdx.x * 32;
    bool isF32 = flags[0] != 0;

    #pragma unroll
    for (int r = 0; r < 4; ++r) {
        int lrow = r * 8 + rg;
        int row = rowBase + lrow;
        float4 v = make_float4(0.f, 0.f, 0.f, 0.f);
        if (row < NN) {
            if (isF32) v = *(const float4*)&((const float*)A)[(long)row * 128 + cg * 4];
            else {
                ushort4 u = *(const ushort4*)&((const unsigned short*)A)[(long)row * 128 + cg * 4];
                v = make_float4(b2f(u.x), b2f(u.y), b2f(u.z), b2f(u.w));
            }
        }
        *(float4*)&As[lrow * 128 + cg * 4] = v;
    }
    float4 bb = *(const float4*)&bias[cg * 4];
    __syncthreads();

    float acc[4][4];
    #pragma unroll
    for (int i = 0; i < 4; ++i) { acc[i][0]=bb.x; acc[i][1]=bb.y; acc[i][2]=bb.z; acc[i][3]=bb.w; }

    #pragma unroll 2
    for (int k4 = 0; k4 < 32; ++k4) {
        float4 w[4], av[4];
        #pragma unroll
        for (int j = 0; j < 4; ++j)
            w[j] = *(const float4*)&W[(k4 * 4 + j) * 128 + cg * 4];
        #pragma unroll
        for (int i = 0; i < 4; ++i)
            av[i] = *(const float4*)&As[(rg * 4 + i) * 128 + k4 * 4];
        #pragma unroll
        for (int i = 0; i < 4; ++i) {
            const float a0 = av[i].x, a1 = av[i].y, a2 = av[i].z, a3 = av[i].w;
            acc[i][0] = fmaf(a0, w[0].x, fmaf(a1, w[1].x, fmaf(a2, w[2].x, fmaf(a3, w[3].x, acc[i][0]))));
            acc[i][1] = fmaf(a0, w[0].y, fmaf(a1, w[1].y, fmaf(a2, w[2].y, fmaf(a3, w[3].y, acc[i][1]))));
            acc[i][2] = fmaf(a0, w[0].z, fmaf(a1, w[1].z, fmaf(a2, w[2].z, fmaf(a3, w[3].z, acc[i][2]))));
            acc[i][3] = fmaf(a0, w[0].w, fmaf(a1, w[1].w, fmaf(a2, w[2].w, fmaf(a3, w[3].w, acc[i][3]))));
        }
    }
    #pragma unroll
    for (int i = 0; i < 4; ++i) {
        int row = rowBase + rg * 4 + i;
        float lss = acc[i][0]*acc[i][0] + acc[i][1]*acc[i][1] + acc[i][2]*acc[i][2] + acc[i][3]*acc[i][3];
        lss += __shfl_xor(lss, 1);
        lss += __shfl_xor(lss, 2);
        lss += __shfl_xor(lss, 4);
        float scale = 1.0f / fmaxf(sqrtf(lss), 1e-12f);
        if (row < NN) {
            float4 o; o.x = acc[i][0]*scale; o.y = acc[i][1]*scale; o.z = acc[i][2]*scale; o.w = acc[i][3]*scale;
            uint2 pk; pk.x = pack2(o.x, o.y); pk.y = pack2(o.z, o.w);
            *(uint2*)((char*)XNh + (long)row * 256 + cg * 8) = pk;
        }
    }
}

// ---- GEMM2: Out = A @ W + b (A fp32, W/bias fp32 prepped) ----
__global__ __launch_bounds__(256) void gemm_plain(
    const float* __restrict__ A, const float* __restrict__ W, const float* __restrict__ bias,
    float* __restrict__ Out)
{
    __shared__ float As[32 * 128];
    int tid = threadIdx.x;
    int cg = tid & 31;
    int rg = tid >> 5;
    int rowBase = blockIdx.x * 32;

    #pragma unroll
    for (int r = 0; r < 4; ++r) {
        int lrow = r * 8 + rg;
        int row = rowBase + lrow;
        float4 v = make_float4(0.f, 0.f, 0.f, 0.f);
        if (row < NN) v = *(const float4*)&A[(long)row * 128 + cg * 4];
        *(float4*)&As[lrow * 128 + cg * 4] = v;
    }
    float4 bb = *(const float4*)&bias[cg * 4];
    __syncthreads();

    float acc[4][4];
    #pragma unroll
    for (int i = 0; i < 4; ++i) { acc[i][0]=bb.x; acc[i][1]=bb.y; acc[i][2]=bb.z; acc[i][3]=bb.w; }

    #pragma unroll 2
    for (int k4 = 0; k4 < 32; ++k4) {
        float4 w[4], av[4];
        #pragma unroll
        for (int j = 0; j < 4; ++j)
            w[j] = *(const float4*)&W[(k4 * 4 + j) * 128 + cg * 4];
        #pragma unroll
        for (int i = 0; i < 4; ++i)
            av[i] = *(const float4*)&As[(rg * 4 + i) * 128 + k4 * 4];
        #pragma unroll
        for (int i = 0; i < 4; ++i) {
            const float a0 = av[i].x, a1 = av[i].y, a2 = av[i].z, a3 = av[i].w;
            acc[i][0] = fmaf(a0, w[0].x, fmaf(a1, w[1].x, fmaf(a2, w[2].x, fmaf(a3, w[3].x, acc[i][0]))));
            acc[i][1] = fmaf(a0, w[0].y, fmaf(a1, w[1].y, fmaf(a2, w[2].y, fmaf(a3, w[3].y, acc[i][1]))));
            acc[i][2] = fmaf(a0, w[0].z, fmaf(a1, w[1].z, fmaf(a2, w[2].z, fmaf(a3, w[3].z, acc[i][2]))));
            acc[i][3] = fmaf(a0, w[0].w, fmaf(a1, w[1].w, fmaf(a2, w[2].w, fmaf(a3, w[3].w, acc[i][3]))));
        }
    }
    #pragma unroll
    for (int i = 0; i < 4; ++i) {
        int row = rowBase + rg * 4 + i;
        if (row < NN) {
            float4 o; o.x = acc[i][0]; o.y = acc[i][1]; o.z = acc[i][2]; o.w = acc[i][3];
            *(float4*)&Out[(long)row * 128 + cg * 4] = o;
        }
    }
}

// ---- fused per-layer routing: 1 wave/node, all 3 iterations, z staged in LDS ----
// v6: v3 structure + SCALAR loop control. beg/end forced to SGPR via readfirstlane
// (node is wave-uniform), so deg/degL/pass counts are scalar -> s_cmp/s_cbranch
// loops, no per-lane exec-mask churn. Staging zero-pads to a 4-row multiple: a
// zero z row contributes exactly 0 (softmax is over the edge's 4 CHANNELS; wgt
// finite x z=0 -> 0), so the PROC loop runs a uniform pass count with no per-edge
// bounds. Overflow loop: uniform pass count + predicated load (z=0 OOB). Dual
// accumulators (a*/b*) keep two independent softmax chains in flight.
#define PROC4(ZU, c0, c1, c2, c3) { \
    f32x2 za0 = {unlo(ZU.x), unhi(ZU.x)}; \
    f32x2 za1 = {unlo(ZU.y), unhi(ZU.y)}; \
    f32x2 za2 = {unlo(ZU.z), unhi(ZU.z)}; \
    f32x2 za3 = {unlo(ZU.w), unhi(ZU.w)}; \
    f32x2 dd_ = za0 * s0; \
    dd_ = __builtin_elementwise_fma(za1, s1, dd_); \
    dd_ = __builtin_elementwise_fma(za2, s2, dd_); \
    dd_ = __builtin_elementwise_fma(za3, s3, dd_); \
    float p_ = dd_.x + dd_.y; \
    p_ = qsum(p_); \
    float ex = EXP2F(p_); \
    float sm = rsum4(ex); \
    float wgt = ex * __builtin_amdgcn_rcpf(sm); \
    f32x2 w2 = {wgt, wgt}; \
    c0 = __builtin_elementwise_fma(w2, za0, c0); \
    c1 = __builtin_elementwise_fma(w2, za1, c1); \
    c2 = __builtin_elementwise_fma(w2, za2, c2); \
    c3 = __builtin_elementwise_fma(w2, za3, c3); }

__global__ __launch_bounds__(256) void route_layer(
    const int* __restrict__ rowStart, const int* __restrict__ eSrc,
    const unsigned short* __restrict__ XNh,
    unsigned short* __restrict__ XNOut, float* __restrict__ CT)
{
    __shared__ unsigned short zbuf[4][CAP * 128];   // 20 KB
    int w = threadIdx.x >> 6;
    int node = blockIdx.x * 4 + w;                  // wave-uniform
    int lane = threadIdx.x & 63;
    int slot = lane >> 4;                           // 4 edge slots
    int h = lane & 15;                              // elems 8h..8h+7, channel h>>2
    // force wave-uniform values into SGPRs -> scalar loop control
    int beg  = __builtin_amdgcn_readfirstlane(rowStart[node]);
    int end  = __builtin_amdgcn_readfirstlane(rowStart[node + 1]);
    int deg  = end - beg;
    int degL = min(deg, CAP);
    int npL  = (degL + 3) >> 2;                     // staged passes (scalar)
    int npO  = (deg > CAP) ? ((deg - CAP + 3) >> 2) : 0;  // overflow passes (scalar)
    const char* XNb = (const char*)XNh;
    int ldsBase = slot * 128 + h * 8;               // lane-constant LDS offset

    // stage npL uniform passes; rows >= degL written as zeros (harmless pads)
    for (int p = 0; p < npL; ++p) {
        int r = p * 4 + slot;
        uint4 v = make_uint4(0u, 0u, 0u, 0u);
        if (r < degL) {
            int src = eSrc[beg + r];
            v = *(const uint4*)(XNb + (src * 256 + h * 16));
        }
        *(uint4*)&zbuf[w][p * 512 + ldsBase] = v;
    }
    // residual xn row (same address for all 4 slots -> L1 broadcast)
    uint4 xr = *(const uint4*)(XNb + (node * 256 + h * 16));
    float x0 = unlo(xr.x), x1 = unhi(xr.x), x2 = unlo(xr.y), x3 = unhi(xr.y);
    float x4 = unlo(xr.z), x5 = unhi(xr.z), x6 = unlo(xr.w), x7 = unhi(xr.w);
    // initial s from xn (already channel-normalized), pre-scaled by log2e
    float tx = (x0 + x1 + x2 + x3) * LOG2E;
    float ty = (x4 + x5 + x6 + x7) * LOG2E;
    int sb = (lane & 48) | (4 * (h & 3));           // slot base + 4*(channel-pos)
    f32x2 s0, s1, s2, s3;
    s0.x = __shfl(tx, sb);     s0.y = __shfl(ty, sb);
    s1.x = __shfl(tx, sb + 1); s1.y = __shfl(ty, sb + 1);
    s2.x = __shfl(tx, sb + 2); s2.y = __shfl(ty, sb + 2);
    s3.x = __shfl(tx, sb + 3); s3.y = __shfl(ty, sb + 3);
    // zbuf is per-wave: only intra-wave ordering of ds_write -> ds_read is needed.
    asm volatile("s_waitcnt lgkmcnt(0)" ::: "memory");

    f32x2 a0, a1, a2, a3;
    #pragma unroll
    for (int iter = 0; iter < 3; ++iter) {
        if (slot == 0) {
            a0 = (f32x2){x0, x1}; a1 = (f32x2){x2, x3};
            a2 = (f32x2){x4, x5}; a3 = (f32x2){x6, x7};
        } else {
            a0 = (f32x2){0.f, 0.f}; a1 = a0; a2 = a0; a3 = a0;
        }
        f32x2 b0 = (f32x2){0.f, 0.f}, b1 = b0, b2 = b0, b3 = b0;  // secondary acc
        // staged edges: uniform pass count, 2x unroll, dual accumulators
        int p = 0;
        for (; p + 2 <= npL; p += 2) {
            uint4 zu0 = *(const uint4*)&zbuf[w][p * 512 + ldsBase];
            uint4 zu1 = *(const uint4*)&zbuf[w][p * 512 + 512 + ldsBase];
            PROC4(zu0, a0, a1, a2, a3);
            PROC4(zu1, b0, b1, b2, b3);
        }
        if (p < npL) {
            uint4 zu = *(const uint4*)&zbuf[w][p * 512 + ldsBase];
            PROC4(zu, a0, a1, a2, a3);
        }
        // overflow edges from global (L2-resident): uniform passes, predicated load
        for (int q = 0; q < npO; ++q) {
            int j = CAP + q * 4 + slot;
            uint4 zu = make_uint4(0u, 0u, 0u, 0u);
            if (j < deg)
                zu = *(const uint4*)(XNb + (eSrc[beg + j] * 256 + h * 16));
            PROC4(zu, b0, b1, b2, b3);
        }
        // merge secondary accumulator
        a0 += b0; a1 += b1; a2 += b2; a3 += b3;
        // combine 4 slots -> every lane holds full c[8h..8h+7]
        a0.x += __shfl_xor(a0.x, 16); a0.x += __shfl_xor(a0.x, 32);
        a0.y += __shfl_xor(a0.y, 16); a0.y += __shfl_xor(a0.y, 32);
        a1.x += __shfl_xor(a1.x, 16); a1.x += __shfl_xor(a1.x, 32);
        a1.y += __shfl_xor(a1.y, 16); a1.y += __shfl_xor(a1.y, 32);
        a2.x += __shfl_xor(a2.x, 16); a2.x += __shfl_xor(a2.x, 32);
        a2.y += __shfl_xor(a2.y, 16); a2.y += __shfl_xor(a2.y, 32);
        a3.x += __shfl_xor(a3.x, 16); a3.x += __shfl_xor(a3.x, 32);
        a3.y += __shfl_xor(a3.y, 16); a3.y += __shfl_xor(a3.y, 32);
        if (iter < 2) {
            // normalize in-register, derive next s (log2e folded), redistribute
            f32x2 q = a0 * a0;
            q = __builtin_elementwise_fma(a1, a1, q);
            q = __builtin_elementwise_fma(a2, a2, q);
            q = __builtin_elementwise_fma(a3, a3, q);
            float ssq = qsum(q.x + q.y);
            float scl = LOG2E / fmaxf(sqrtf(ssq), 1e-12f);
            tx = (a0.x + a0.y + a1.x + a1.y) * scl;
            ty = (a2.x + a2.y + a3.x + a3.y) * scl;
            s0.x = __shfl(tx, sb);     s0.y = __shfl(ty, sb);
            s1.x = __shfl(tx, sb + 1); s1.y = __shfl(ty, sb + 1);
            s2.x = __shfl(tx, sb + 2); s2.y = __shfl(ty, sb + 2);
            s3.x = __shfl(tx, sb + 3); s3.y = __shfl(ty, sb + 3);
        }
    }
    // epilogue
    if (XNOut) {   // layer 1: write channel-normalized bf16 (next layer's xn)
        f32x2 q = a0 * a0;
        q = __builtin_elementwise_fma(a1, a1, q);
        q = __builtin_elementwise_fma(a2, a2, q);
        q = __builtin_elementwise_fma(a3, a3, q);
        float ssq = qsum(q.x + q.y);
        float scale = 1.0f / fmaxf(sqrtf(ssq), 1e-12f);
        if (slot == 0) {
            uint4 pk;
            pk.x = pack2(a0.x * scale, a0.y * scale);
            pk.y = pack2(a1.x * scale, a1.y * scale);
            pk.z = pack2(a2.x * scale, a2.y * scale);
            pk.w = pack2(a3.x * scale, a3.y * scale);
            *(uint4*)((char*)XNOut + (node * 256 + h * 16)) = pk;
        }
    }
    if (CT && slot == 0) {   // layer 2: raw fp32 x
        float4* cp = (float4*)(CT + (node * 128 + 8 * h));
        cp[0] = make_float4(a0.x, a0.y, a1.x, a1.y);
        cp[1] = make_float4(a2.x, a2.y, a3.x, a3.y);
    }
}

extern "C" void kernel_launch(void* const* d_in, const int* in_sizes, int n_in,
                              void* d_out, int out_size, void* d_ws, size_t ws_size,
                              hipStream_t stream) {
    const void* feat  = d_in[0];
    const void* ei    = d_in[1];
    const void* lin_w = d_in[2];
    const void* lin_b = d_in[3];
    const void* mlp_w = d_in[4];
    const void* mlp_b = d_in[5];
    float* out = (float*)d_out;               // [out(N,128) | x(N,128)] fp32

    const int m = in_sizes[1] / 2;            // 800000 edges

    // ---- workspace layout ----
    char* wsB = (char*)d_ws;
    int*   flags = (int*)wsB;                                  // 256 B slot
    unsigned short* XH1 = (unsigned short*)(wsB + 256);        // NN*128 bf16
    unsigned short* XH2 = XH1 + ND;                            // NN*128 bf16
    int*   eSrc  = (int*)(XH2 + ND);                           // m
    int*   deg   = eSrc + m;                                   // NN
    int*   rowStart = deg + NN;                                // NN+1
    int*   cursor   = rowStart + NN + 1;                       // NN
    int*   blkSum   = cursor + NN;                             // 64
    int*   blkOff   = blkSum + 64;                             // 64
    float* W1f      = (float*)(blkOff + 64);                   // 16384
    float* B1f      = W1f + 16384;                             // 128
    float* W2f      = B1f + 128;                               // 16384
    float* B2f      = W2f + 16384;                             // 128

    hipMemsetAsync(flags, 0, 8, stream);
    hipMemsetAsync(deg, 0, NN * sizeof(int), stream);
    detect<<<1, 256, 0, stream>>>((const unsigned short*)feat, (const unsigned int*)ei, flags);
    prep_w<<<64, 256, 0, stream>>>(lin_w, lin_b, mlp_w, mlp_b, W1f, B1f, W2f, B2f, flags);

    const int edgeBlocks = (m + 255) / 256;
    conv_hist<<<edgeBlocks, 256, 0, stream>>>(ei, deg, m, flags);
    scan1<<<SCAN_B, 256, 0, stream>>>(deg, rowStart, blkSum);
    scan2<<<1, 64, 0, stream>>>(blkSum, blkOff, rowStart, m);
    scan3<<<SCAN_B, 256, 0, stream>>>(rowStart, blkOff, cursor);
    scatter_csr<<<edgeBlocks, 256, 0, stream>>>(ei, cursor, eSrc, m, flags);

    const int gemmBlocks = (NN + 31) / 32;
    const int nodeBlocks = NN / 4;            // NN % 4 == 0

    // gemm1 + fused normalize: feat -> XH1 (bf16)
    gemm_norm<<<gemmBlocks, 256, 0, stream>>>(feat, W1f, B1f, XH1, flags);

    // layer 1: all 3 routing iterations fused; writes normalized bf16 XH2
    route_layer<<<nodeBlocks, 256, 0, stream>>>(rowStart, eSrc, XH1, XH2, nullptr);
    // layer 2: writes raw fp32 x -> out+ND
    route_layer<<<nodeBlocks, 256, 0, stream>>>(rowStart, eSrc, XH2, nullptr, out + ND);

    // out = x @ mlp_w + mlp_b, reading x straight from out+ND
    gemm_plain<<<gemmBlocks, 256, 0, stream>>>(out + ND, W2f, B2f, out);
}

// Round 6
// 389.379 us; speedup vs baseline: 1.0737x; 1.0130x over previous
//
#include <hip/hip_runtime.h>

#define NN 50000
#define ND (NN * 128)
#define SCAN_B 49   // ceil(NN / 1024)
#define CAP 20      // LDS-cached neighbor rows per node (best measured: v3 @ 75.6us)
#define LOG2E 1.4426950408889634f

typedef float f32x2 __attribute__((ext_vector_type(2)));

#if defined(__has_builtin)
#  if __has_builtin(__builtin_amdgcn_exp2f)
#    define EXP2F(x) __builtin_amdgcn_exp2f(x)
#  else
#    define EXP2F(x) exp2f(x)
#  endif
#else
#  define EXP2F(x) exp2f(x)
#endif

__device__ __forceinline__ float b2f(unsigned short u) {
    union { unsigned int i; float f; } v; v.i = ((unsigned int)u) << 16; return v.f;
}
__device__ __forceinline__ unsigned short f2b(float f) {      // RNE bf16 pack
    union { float f; unsigned int i; } v; v.f = f;
    return (unsigned short)((v.i + 0x7fffu + ((v.i >> 16) & 1u)) >> 16);
}
__device__ __forceinline__ unsigned int pack2(float lo, float hi) {
    return (unsigned int)f2b(lo) | ((unsigned int)f2b(hi) << 16);
}
__device__ __forceinline__ float unlo(unsigned int u) { return __uint_as_float(u << 16); }
__device__ __forceinline__ float unhi(unsigned int u) { return __uint_as_float(u & 0xFFFF0000u); }
__device__ __forceinline__ int clampi(int i, int lo, int hi) { return max(lo, min(i, hi)); }

// DPP lane ops (VALU pipe, no LDS traffic). All patterns stay within a 16-lane row.
template<int CTRL>
__device__ __forceinline__ float dmov(float v) {
    return __int_as_float(__builtin_amdgcn_update_dpp(0, __float_as_int(v), CTRL, 0xF, 0xF, true));
}
template<int CTRL> __device__ __forceinline__ float dadd(float v) { return v + dmov<CTRL>(v); }
__device__ __forceinline__ float qsum(float v) { v = dadd<0xB1>(v); v = dadd<0x4E>(v); return v; }
__device__ __forceinline__ float rsum4(float v) { v = dadd<0x124>(v); v = dadd<0x128>(v); return v; }

// ---- dtype detection (also zeroes flags itself: single block) ----
__global__ __launch_bounds__(256) void detect(
    const unsigned short* __restrict__ feat_u, const unsigned int* __restrict__ ei_u,
    int* __restrict__ flags)
{
    int tid = threadIdx.x;
    if (tid == 0) { flags[0] = 0; flags[1] = 0; }
    __syncthreads();
    int f32hit = 0;
    for (int i = tid; i < 8192; i += 256) {
        unsigned e = (feat_u[i] >> 7) & 0xFFu;
        if (e >= 0xC0u) f32hit = 1;
    }
    int i32hit = 0;
    for (int i = tid; i < 4096; i += 256)
        if (ei_u[2 * i + 1] != 0u) i32hit = 1;
    if (f32hit) atomicOr(&flags[0], 1);
    if (i32hit) atomicOr(&flags[1], 1);
}

// ---- one-time W/bias -> fp32 workspace; also zeroes deg[] (runs before conv_hist) ----
__global__ __launch_bounds__(256) void prep_w(
    const void* __restrict__ W1, const void* __restrict__ B1,
    const void* __restrict__ W2, const void* __restrict__ B2,
    float* __restrict__ w1o, float* __restrict__ b1o,
    float* __restrict__ w2o, float* __restrict__ b2o,
    int* __restrict__ deg, const int* __restrict__ flags)
{
    bool isF32 = flags[0] != 0;
    int idx = blockIdx.x * 256 + threadIdx.x;
    if (idx < 16384) {
        if (isF32) { w1o[idx] = ((const float*)W1)[idx]; w2o[idx] = ((const float*)W2)[idx]; }
        else {
            w1o[idx] = b2f(((const unsigned short*)W1)[idx]);
            w2o[idx] = b2f(((const unsigned short*)W2)[idx]);
        }
    }
    if (idx < 128) {
        if (isF32) { b1o[idx] = ((const float*)B1)[idx]; b2o[idx] = ((const float*)B2)[idx]; }
        else {
            b1o[idx] = b2f(((const unsigned short*)B1)[idx]);
            b2o[idx] = b2f(((const unsigned short*)B2)[idx]);
        }
    }
    for (int i = idx; i < NN; i += 64 * 256) deg[i] = 0;
}

// ---- degree histogram (reads trg half of raw edge list only) ----
__global__ __launch_bounds__(256) void conv_hist(
    const void* __restrict__ eiRaw, int* __restrict__ deg, int m,
    const int* __restrict__ flags)
{
    int e = blockIdx.x * 256 + threadIdx.x;
    if (e >= m) return;
    int trg;
    if (flags[1]) trg = ((const int*)eiRaw)[m + e];
    else          trg = (int)((const long long*)eiRaw)[m + e];
    trg = clampi(trg, 0, NN - 1);
    atomicAdd(&deg[trg], 1);
}

// ---- exclusive scan of deg[NN]: pass 1 (per-1024-chunk) ----
__global__ __launch_bounds__(256) void scan1(
    const int* __restrict__ deg, int* __restrict__ rowStart, int* __restrict__ blkSum)
{
    __shared__ int lds[256];
    int blk = blockIdx.x, tid = threadIdx.x;
    int base = blk * 1024 + tid * 4;
    int v[4]; int s = 0;
    #pragma unroll
    for (int j = 0; j < 4; ++j) { int idx = base + j; v[j] = (idx < NN) ? deg[idx] : 0; s += v[j]; }
    lds[tid] = s; __syncthreads();
    for (int off = 1; off < 256; off <<= 1) {
        int x = (tid >= off) ? lds[tid - off] : 0;
        __syncthreads();
        lds[tid] += x;
        __syncthreads();
    }
    int excl = lds[tid] - s;
    if (tid == 255) blkSum[blk] = lds[tid];
    int run = excl;
    #pragma unroll
    for (int j = 0; j < 4; ++j) { int idx = base + j; if (idx < NN) rowStart[idx] = run; run += v[j]; }
}

// ---- scan pass 2: each block recomputes the 49-wide block-offset scan in its
// first wave (replaces the old scan2 dispatch), applies it, seeds cursor ----
__global__ __launch_bounds__(256) void scan3(
    int* __restrict__ rowStart, const int* __restrict__ blkSum,
    int* __restrict__ cursor, int m)
{
    __shared__ int soff;
    int tid = threadIdx.x;
    if (tid < 64) {
        int orig = (tid < SCAN_B) ? blkSum[tid] : 0;
        int v = orig;
        for (int off = 1; off < 64; off <<= 1) {
            int x = __shfl_up(v, off);
            if (tid >= off) v += x;
        }
        if (tid == (int)blockIdx.x) soff = v - orig;   // exclusive prefix at blockIdx
        if (blockIdx.x == 0 && tid == 0) rowStart[NN] = m;
    }
    __syncthreads();
    int off = soff;
    int base = blockIdx.x * 1024 + tid * 4;
    #pragma unroll
    for (int j = 0; j < 4; ++j) {
        int idx = base + j;
        if (idx < NN) { int v = rowStart[idx] + off; rowStart[idx] = v; cursor[idx] = v; }
    }
}

// ---- scatter edges into CSR bins (re-reads raw edge list) ----
__global__ __launch_bounds__(256) void scatter_csr(
    const void* __restrict__ eiRaw, int* __restrict__ cursor, int* __restrict__ eSrc,
    int m, const int* __restrict__ flags)
{
    int e = blockIdx.x * 256 + threadIdx.x;
    if (e >= m) return;
    int src, trg;
    if (flags[1]) { const int* p = (const int*)eiRaw; src = p[e]; trg = p[m + e]; }
    else { const long long* p = (const long long*)eiRaw; src = (int)p[e]; trg = (int)p[m + e]; }
    src = clampi(src, 0, NN - 1);
    trg = clampi(trg, 0, NN - 1);
    int pos = atomicAdd(&cursor[trg], 1);
    eSrc[pos] = src;
}

// ---- GEMM1: XNh(bf16) = channel_normalize(feat @ W + b). W/bias fp32 (prepped).
__global__ __launch_bounds__(256) void gemm_norm(
    const void* __restrict__ A, const float* __restrict__ W, const float* __restrict__ bias,
    unsigned short* __restrict__ XNh, const int* __restrict__ flags)
{
    __shared__ float As[32 * 128];
    int tid = threadIdx.x;
    int cg = tid & 31;                // cols 4cg..4cg+3
    int rg = tid >> 5;                // rows rg*4..rg*4+3 (of 32)
    int rowBase = blockIdx.x * 32;
    bool isF32 = flags[0] != 0;

    #pragma unroll
    for (int r = 0; r < 4; ++r) {
        int lrow = r * 8 + rg;
        int row = rowBase + lrow;
        float4 v = make_float4(0.f, 0.f, 0.f, 0.f);
        if (row < NN) {
            if (isF32) v = *(const float4*)&((const float*)A)[(long)row * 128 + cg * 4];
            else {
                ushort4 u = *(const ushort4*)&((const unsigned short*)A)[(long)row * 128 + cg * 4];
                v = make_float4(b2f(u.x), b2f(u.y), b2f(u.z), b2f(u.w));
            }
        }
        *(float4*)&As[lrow * 128 + cg * 4] = v;
    }
    float4 bb = *(const float4*)&bias[cg * 4];
    __syncthreads();

    float acc[4][4];
    #pragma unroll
    for (int i = 0; i < 4; ++i) { acc[i][0]=bb.x; acc[i][1]=bb.y; acc[i][2]=bb.z; acc[i][3]=bb.w; }

    #pragma unroll 2
    for (int k4 = 0; k4 < 32; ++k4) {
        float4 w[4], av[4];
        #pragma unroll
        for (int j = 0; j < 4; ++j)
            w[j] = *(const float4*)&W[(k4 * 4 + j) * 128 + cg * 4];
        #pragma unroll
        for (int i = 0; i < 4; ++i)
            av[i] = *(const float4*)&As[(rg * 4 + i) * 128 + k4 * 4];
        #pragma unroll
        for (int i = 0; i < 4; ++i) {
            const float a0 = av[i].x, a1 = av[i].y, a2 = av[i].z, a3 = av[i].w;
            acc[i][0] = fmaf(a0, w[0].x, fmaf(a1, w[1].x, fmaf(a2, w[2].x, fmaf(a3, w[3].x, acc[i][0]))));
            acc[i][1] = fmaf(a0, w[0].y, fmaf(a1, w[1].y, fmaf(a2, w[2].y, fmaf(a3, w[3].y, acc[i][1]))));
            acc[i][2] = fmaf(a0, w[0].z, fmaf(a1, w[1].z, fmaf(a2, w[2].z, fmaf(a3, w[3].z, acc[i][2]))));
            acc[i][3] = fmaf(a0, w[0].w, fmaf(a1, w[1].w, fmaf(a2, w[2].w, fmaf(a3, w[3].w, acc[i][3]))));
        }
    }
    #pragma unroll
    for (int i = 0; i < 4; ++i) {
        int row = rowBase + rg * 4 + i;
        float lss = acc[i][0]*acc[i][0] + acc[i][1]*acc[i][1] + acc[i][2]*acc[i][2] + acc[i][3]*acc[i][3];
        lss += __shfl_xor(lss, 1);
        lss += __shfl_xor(lss, 2);
        lss += __shfl_xor(lss, 4);
        float scale = 1.0f / fmaxf(sqrtf(lss), 1e-12f);
        if (row < NN) {
            float4 o; o.x = acc[i][0]*scale; o.y = acc[i][1]*scale; o.z = acc[i][2]*scale; o.w = acc[i][3]*scale;
            uint2 pk; pk.x = pack2(o.x, o.y); pk.y = pack2(o.z, o.w);
            *(uint2*)((char*)XNh + (long)row * 256 + cg * 8) = pk;
        }
    }
}

// ---- GEMM2: Out = A @ W + b (A fp32, W/bias fp32 prepped) ----
__global__ __launch_bounds__(256) void gemm_plain(
    const float* __restrict__ A, const float* __restrict__ W, const float* __restrict__ bias,
    float* __restrict__ Out)
{
    __shared__ float As[32 * 128];
    int tid = threadIdx.x;
    int cg = tid & 31;
    int rg = tid >> 5;
    int rowBase = blockIdx.x * 32;

    #pragma unroll
    for (int r = 0; r < 4; ++r) {
        int lrow = r * 8 + rg;
        int row = rowBase + lrow;
        float4 v = make_float4(0.f, 0.f, 0.f, 0.f);
        if (row < NN) v = *(const float4*)&A[(long)row * 128 + cg * 4];
        *(float4*)&As[lrow * 128 + cg * 4] = v;
    }
    float4 bb = *(const float4*)&bias[cg * 4];
    __syncthreads();

    float acc[4][4];
    #pragma unroll
    for (int i = 0; i < 4; ++i) { acc[i][0]=bb.x; acc[i][1]=bb.y; acc[i][2]=bb.z; acc[i][3]=bb.w; }

    #pragma unroll 2
    for (int k4 = 0; k4 < 32; ++k4) {
        float4 w[4], av[4];
        #pragma unroll
        for (int j = 0; j < 4; ++j)
            w[j] = *(const float4*)&W[(k4 * 4 + j) * 128 + cg * 4];
        #pragma unroll
        for (int i = 0; i < 4; ++i)
            av[i] = *(const float4*)&As[(rg * 4 + i) * 128 + k4 * 4];
        #pragma unroll
        for (int i = 0; i < 4; ++i) {
            const float a0 = av[i].x, a1 = av[i].y, a2 = av[i].z, a3 = av[i].w;
            acc[i][0] = fmaf(a0, w[0].x, fmaf(a1, w[1].x, fmaf(a2, w[2].x, fmaf(a3, w[3].x, acc[i][0]))));
            acc[i][1] = fmaf(a0, w[0].y, fmaf(a1, w[1].y, fmaf(a2, w[2].y, fmaf(a3, w[3].y, acc[i][1]))));
            acc[i][2] = fmaf(a0, w[0].z, fmaf(a1, w[1].z, fmaf(a2, w[2].z, fmaf(a3, w[3].z, acc[i][2]))));
            acc[i][3] = fmaf(a0, w[0].w, fmaf(a1, w[1].w, fmaf(a2, w[2].w, fmaf(a3, w[3].w, acc[i][3]))));
        }
    }
    #pragma unroll
    for (int i = 0; i < 4; ++i) {
        int row = rowBase + rg * 4 + i;
        if (row < NN) {
            float4 o; o.x = acc[i][0]; o.y = acc[i][1]; o.z = acc[i][2]; o.w = acc[i][3];
            *(float4*)&Out[(long)row * 128 + cg * 4] = o;
        }
    }
}

// ---- fused per-layer routing: exact v3 structure (best measured: 75.6us) ----
// 1 wave/node, all 3 iterations fused, z staged in LDS (CAP 20), packed-fp32 math,
// no softmax max-sub (|p|<=4 since z rows are unit-norm per channel), log2e folded.
#define PROC(ZU) { \
    f32x2 za0 = {unlo(ZU.x), unhi(ZU.x)}; \
    f32x2 za1 = {unlo(ZU.y), unhi(ZU.y)}; \
    f32x2 za2 = {unlo(ZU.z), unhi(ZU.z)}; \
    f32x2 za3 = {unlo(ZU.w), unhi(ZU.w)}; \
    f32x2 dd_ = za0 * s0; \
    dd_ = __builtin_elementwise_fma(za1, s1, dd_); \
    dd_ = __builtin_elementwise_fma(za2, s2, dd_); \
    dd_ = __builtin_elementwise_fma(za3, s3, dd_); \
    float p = dd_.x + dd_.y; \
    p = qsum(p); \
    float ex = EXP2F(p); \
    float sm = rsum4(ex); \
    float wgt = ex * __builtin_amdgcn_rcpf(sm); \
    f32x2 w2 = {wgt, wgt}; \
    a0 = __builtin_elementwise_fma(w2, za0, a0); \
    a1 = __builtin_elementwise_fma(w2, za1, a1); \
    a2 = __builtin_elementwise_fma(w2, za2, a2); \
    a3 = __builtin_elementwise_fma(w2, za3, a3); }

__global__ __launch_bounds__(256) void route_layer(
    const int* __restrict__ rowStart, const int* __restrict__ eSrc,
    const unsigned short* __restrict__ XNh,
    unsigned short* __restrict__ XNOut, float* __restrict__ CT)
{
    __shared__ unsigned short zbuf[4][CAP * 128];   // 20 KB
    int w = threadIdx.x >> 6;
    int node = blockIdx.x * 4 + w;                  // NN % 4 == 0: always valid
    int lane = threadIdx.x & 63;
    int slot = lane >> 4;                           // 4 edge slots
    int h = lane & 15;                              // elems 8h..8h+7, channel h>>2
    int beg = rowStart[node], end = rowStart[node + 1];
    int deg = end - beg;
    int degL = min(deg, CAP);
    const char* XNb = (const char*)XNh;

    // stage neighbor z rows into this wave's LDS slab: 16 lanes per row, 4 rows/pass
    for (int r = slot; r < degL; r += 4) {
        int src = eSrc[beg + r];
        uint4 v = *(const uint4*)(XNb + (src * 256 + h * 16));
        *(uint4*)&zbuf[w][r * 128 + h * 8] = v;
    }
    // residual xn row (same address for all 4 slots -> L1 broadcast)
    uint4 xr = *(const uint4*)(XNb + (node * 256 + h * 16));
    float x0 = unlo(xr.x), x1 = unhi(xr.x), x2 = unlo(xr.y), x3 = unhi(xr.y);
    float x4 = unlo(xr.z), x5 = unhi(xr.z), x6 = unlo(xr.w), x7 = unhi(xr.w);
    // initial s from xn (already channel-normalized), pre-scaled by log2e
    float tx = (x0 + x1 + x2 + x3) * LOG2E;
    float ty = (x4 + x5 + x6 + x7) * LOG2E;
    int sb = (lane & 48) | (4 * (h & 3));           // slot base + 4*(channel-pos)
    f32x2 s0, s1, s2, s3;
    s0.x = __shfl(tx, sb);     s0.y = __shfl(ty, sb);
    s1.x = __shfl(tx, sb + 1); s1.y = __shfl(ty, sb + 1);
    s2.x = __shfl(tx, sb + 2); s2.y = __shfl(ty, sb + 2);
    s3.x = __shfl(tx, sb + 3); s3.y = __shfl(ty, sb + 3);
    // zbuf is per-wave: only intra-wave ordering of ds_write -> ds_read is needed.
    asm volatile("s_waitcnt lgkmcnt(0)" ::: "memory");

    f32x2 a0, a1, a2, a3;
    #pragma unroll
    for (int iter = 0; iter < 3; ++iter) {
        if (slot == 0) {
            a0 = (f32x2){x0, x1}; a1 = (f32x2){x2, x3};
            a2 = (f32x2){x4, x5}; a3 = (f32x2){x6, x7};
        } else {
            a0 = (f32x2){0.f, 0.f}; a1 = a0; a2 = a0; a3 = a0;
        }
        // LDS-resident edges: branch-free, 2x unrolled
        int i = slot;
        for (; i + 4 < degL; i += 8) {
            uint4 zu0 = *(const uint4*)&zbuf[w][i * 128 + h * 8];
            uint4 zu1 = *(const uint4*)&zbuf[w][(i + 4) * 128 + h * 8];
            PROC(zu0);
            PROC(zu1);
        }
        if (i < degL) {
            uint4 zu = *(const uint4*)&zbuf[w][i * 128 + h * 8];
            PROC(zu);
        }
        // rare overflow edges straight from global (L2-resident)
        for (int j = CAP + slot; j < deg; j += 4) {
            uint4 zu = *(const uint4*)(XNb + (eSrc[beg + j] * 256 + h * 16));
            PROC(zu);
        }
        // combine 4 slots -> every lane holds full c[8h..8h+7]
        a0.x += __shfl_xor(a0.x, 16); a0.x += __shfl_xor(a0.x, 32);
        a0.y += __shfl_xor(a0.y, 16); a0.y += __shfl_xor(a0.y, 32);
        a1.x += __shfl_xor(a1.x, 16); a1.x += __shfl_xor(a1.x, 32);
        a1.y += __shfl_xor(a1.y, 16); a1.y += __shfl_xor(a1.y, 32);
        a2.x += __shfl_xor(a2.x, 16); a2.x += __shfl_xor(a2.x, 32);
        a2.y += __shfl_xor(a2.y, 16); a2.y += __shfl_xor(a2.y, 32);
        a3.x += __shfl_xor(a3.x, 16); a3.x += __shfl_xor(a3.x, 32);
        a3.y += __shfl_xor(a3.y, 16); a3.y += __shfl_xor(a3.y, 32);
        if (iter < 2) {
            // normalize in-register, derive next s (log2e folded), redistribute
            f32x2 q = a0 * a0;
            q = __builtin_elementwise_fma(a1, a1, q);
            q = __builtin_elementwise_fma(a2, a2, q);
            q = __builtin_elementwise_fma(a3, a3, q);
            float ssq = qsum(q.x + q.y);
            float scl = LOG2E / fmaxf(sqrtf(ssq), 1e-12f);
            tx = (a0.x + a0.y + a1.x + a1.y) * scl;
            ty = (a2.x + a2.y + a3.x + a3.y) * scl;
            s0.x = __shfl(tx, sb);     s0.y = __shfl(ty, sb);
            s1.x = __shfl(tx, sb + 1); s1.y = __shfl(ty, sb + 1);
            s2.x = __shfl(tx, sb + 2); s2.y = __shfl(ty, sb + 2);
            s3.x = __shfl(tx, sb + 3); s3.y = __shfl(ty, sb + 3);
        }
    }
    // epilogue
    if (XNOut) {   // layer 1: write channel-normalized bf16 (next layer's xn)
        f32x2 q = a0 * a0;
        q = __builtin_elementwise_fma(a1, a1, q);
        q = __builtin_elementwise_fma(a2, a2, q);
        q = __builtin_elementwise_fma(a3, a3, q);
        float ssq = qsum(q.x + q.y);
        float scale = 1.0f / fmaxf(sqrtf(ssq), 1e-12f);
        if (slot == 0) {
            uint4 pk;
            pk.x = pack2(a0.x * scale, a0.y * scale);
            pk.y = pack2(a1.x * scale, a1.y * scale);
            pk.z = pack2(a2.x * scale, a2.y * scale);
            pk.w = pack2(a3.x * scale, a3.y * scale);
            *(uint4*)((char*)XNOut + (node * 256 + h * 16)) = pk;
        }
    }
    if (CT && slot == 0) {   // layer 2: raw fp32 x
        float4* cp = (float4*)(CT + (node * 128 + 8 * h));
        cp[0] = make_float4(a0.x, a0.y, a1.x, a1.y);
        cp[1] = make_float4(a2.x, a2.y, a3.x, a3.y);
    }
}

extern "C" void kernel_launch(void* const* d_in, const int* in_sizes, int n_in,
                              void* d_out, int out_size, void* d_ws, size_t ws_size,
                              hipStream_t stream) {
    const void* feat  = d_in[0];
    const void* ei    = d_in[1];
    const void* lin_w = d_in[2];
    const void* lin_b = d_in[3];
    const void* mlp_w = d_in[4];
    const void* mlp_b = d_in[5];
    float* out = (float*)d_out;               // [out(N,128) | x(N,128)] fp32

    const int m = in_sizes[1] / 2;            // 800000 edges

    // ---- workspace layout ----
    char* wsB = (char*)d_ws;
    int*   flags = (int*)wsB;                                  // 256 B slot
    unsigned short* XH1 = (unsigned short*)(wsB + 256);        // NN*128 bf16
    unsigned short* XH2 = XH1 + ND;                            // NN*128 bf16
    int*   eSrc  = (int*)(XH2 + ND);                           // m
    int*   deg   = eSrc + m;                                   // NN
    int*   rowStart = deg + NN;                                // NN+1
    int*   cursor   = rowStart + NN + 1;                       // NN
    int*   blkSum   = cursor + NN;                             // 64
    float* W1f      = (float*)(blkSum + 64);                   // 16384
    float* B1f      = W1f + 16384;                             // 128
    float* W2f      = B1f + 128;                               // 16384
    float* B2f      = W2f + 16384;                             // 128

    // 10 dispatches, zero memsets: detect zeroes flags, prep_w zeroes deg,
    // scan2 folded into scan3.
    detect<<<1, 256, 0, stream>>>((const unsigned short*)feat, (const unsigned int*)ei, flags);
    prep_w<<<64, 256, 0, stream>>>(lin_w, lin_b, mlp_w, mlp_b, W1f, B1f, W2f, B2f, deg, flags);

    const int edgeBlocks = (m + 255) / 256;
    conv_hist<<<edgeBlocks, 256, 0, stream>>>(ei, deg, m, flags);
    scan1<<<SCAN_B, 256, 0, stream>>>(deg, rowStart, blkSum);
    scan3<<<SCAN_B, 256, 0, stream>>>(rowStart, blkSum, cursor, m);
    scatter_csr<<<edgeBlocks, 256, 0, stream>>>(ei, cursor, eSrc, m, flags);

    const int gemmBlocks = (NN + 31) / 32;
    const int nodeBlocks = NN / 4;            // NN % 4 == 0

    // gemm1 + fused normalize: feat -> XH1 (bf16)
    gemm_norm<<<gemmBlocks, 256, 0, stream>>>(feat, W1f, B1f, XH1, flags);

    // layer 1: all 3 routing iterations fused; writes normalized bf16 XH2
    route_layer<<<nodeBlocks, 256, 0, stream>>>(rowStart, eSrc, XH1, XH2, nullptr);
    // layer 2: writes raw fp32 x -> out+ND
    route_layer<<<nodeBlocks, 256, 0, stream>>>(rowStart, eSrc, XH2, nullptr, out + ND);

    // out = x @ mlp_w + mlp_b, reading x straight from out+ND
    gemm_plain<<<gemmBlocks, 256, 0, stream>>>(out + ND, W2f, B2f, out);
}